// Round 3
// baseline (396.561 us; speedup 1.0000x reference)
//
#include <hip/hip_runtime.h>
#include <stdint.h>

#define BATCH 2
#define SEQ   2048
#define DIM   1024
#define NH    16
#define DH    64

typedef short bf16x8 __attribute__((ext_vector_type(8)));
typedef float floatx4 __attribute__((ext_vector_type(4)));

__device__ __forceinline__ int swz(int r) { return (r ^ (r >> 2)) & 3; }

// fast 2^x: raw v_exp_f32
#if __has_builtin(__builtin_amdgcn_exp2f)
#define EXP2(x) __builtin_amdgcn_exp2f(x)
#else
#define EXP2(x) __expf((x) * 0.6931471805599453f)
#endif

// Split two fp32 into packed bf16 hi-pair and lo-pair (truncation split)
__device__ __forceinline__ void split2(float x0, float x1, uint32_t& hi, uint32_t& lo) {
    uint32_t u0 = __float_as_uint(x0), u1 = __float_as_uint(x1);
    uint32_t m0 = u0 & 0xFFFF0000u;
    uint32_t m1 = u1 & 0xFFFF0000u;
    hi = (u0 >> 16) | m1;
    float l0 = x0 - __uint_as_float(m0);
    float l1 = x1 - __uint_as_float(m1);
    lo = (__float_as_uint(l0) >> 16) | (__float_as_uint(l1) & 0xFFFF0000u);
}

__device__ __forceinline__ uint32_t pack_bf16_rne(float x0, float x1) {
    uint32_t u0 = __float_as_uint(x0), u1 = __float_as_uint(x1);
    u0 += 0x7FFFu + ((u0 >> 16) & 1);
    u1 += 0x7FFFu + ((u1 >> 16) & 1);
    return (u0 >> 16) | (u1 & 0xFFFF0000u);
}

__device__ __forceinline__ ushort bf16_rne1(float x) {
    uint32_t u = __float_as_uint(x);
    u += 0x7FFFu + ((u >> 16) & 1);
    return (ushort)(u >> 16);
}

// softmax scale folded into K: 0.125 * log2(e) -> flash uses exp2
#define KSCALE 0.18033688011112042f

// ---------------- fused qv+k projection GEMM -------------------------------
// B-staging store order: nn = i ^ nsel (nsel = lane bit) makes bank bit 4
// (n&1) vary WITHIN each store instruction -> 8-way conflict becomes the
// structural 4/bank minimum. Global-load mapping unchanged (512B segments).
__global__ __launch_bounds__(256, 3)
void gemm_qvk(const float* __restrict__ Aqv, const float* __restrict__ Akp,
              const float* __restrict__ Wqv, const float* __restrict__ Wkp,
              uint32_t* __restrict__ qh, uint32_t* __restrict__ ql,
              ushort* __restrict__ vt,
              uint32_t* __restrict__ kh, uint32_t* __restrict__ kl)
{
    __shared__ uint32_t Ah[128 * 16], Al[128 * 16], Bh[128 * 16], Bl[128 * 16];

    const int t    = threadIdx.x;
    const int lane = t & 63;
    const int w    = t >> 6;
    const int wm   = w & 1, wn = w >> 1;
    const int quad = lane >> 4, l15 = lane & 15;
    const int bx   = blockIdx.x;
    const bool is_qv = (bx < 16);
    const float* Af = is_qv ? Aqv : Akp;
    const float* Bf = is_qv ? Wqv : Wkp;
    const int N    = is_qv ? 2048 : 1024;
    const int n0   = (is_qv ? bx : bx - 16) * 128;
    const int m0   = blockIdx.y * 128;

    const int ar  = t >> 1;
    const int ab0 = (t & 1) * 2;
    const int as  = swz(ar);
    const int bc  = (t & 31) * 4;
    const int bk  = (t >> 5) * 4;
    const int bb  = bk >> 3;
    const int bp  = (bk & 7) >> 1;
    const int nsel = (bc >> 4) & 1;      // lane-varying store-order selector

    floatx4 acc[4][4];
    #pragma unroll
    for (int i = 0; i < 4; i++)
        #pragma unroll
        for (int j = 0; j < 4; j++)
            #pragma unroll
            for (int e = 0; e < 4; e++) acc[i][j][e] = 0.0f;

    for (int k0 = 0; k0 < 1024; k0 += 32) {
        if (k0) __syncthreads();
        {
            float f[16];
            #pragma unroll
            for (int i = 0; i < 4; i++)
                *(float4*)&f[i * 4] =
                    *(const float4*)&Af[(size_t)(m0 + ar) * 1024 + k0 + ab0 * 8 + i * 4];
            uint32_t hi[8], lo[8];
            #pragma unroll
            for (int j = 0; j < 8; j++) split2(f[2 * j], f[2 * j + 1], hi[j], lo[j]);
            int i0 = ar * 16 + ((ab0 ^ as) * 4);
            int i1 = ar * 16 + (((ab0 + 1) ^ as) * 4);
            *(uint4*)&Ah[i0] = make_uint4(hi[0], hi[1], hi[2], hi[3]);
            *(uint4*)&Ah[i1] = make_uint4(hi[4], hi[5], hi[6], hi[7]);
            *(uint4*)&Al[i0] = make_uint4(lo[0], lo[1], lo[2], lo[3]);
            *(uint4*)&Al[i1] = make_uint4(lo[4], lo[5], lo[6], lo[7]);
        }
        {
            float4 g4[4];
            #pragma unroll
            for (int j = 0; j < 4; j++)
                g4[j] = *(const float4*)&Bf[(size_t)(k0 + bk + j) * N + n0 + bc];
            #pragma unroll
            for (int i = 0; i < 4; i++) {
                int nn = i ^ nsel;           // bijective per-lane column order
                int n = bc + nn;
                float e0 = ((const float*)&g4[0])[nn];
                float e1 = ((const float*)&g4[1])[nn];
                float e2 = ((const float*)&g4[2])[nn];
                float e3 = ((const float*)&g4[3])[nn];
                uint32_t h0, q0, h1, q1;
                split2(e0, e1, h0, q0);
                split2(e2, e3, h1, q1);
                int bi = n * 16 + ((bb ^ swz(n)) * 4) + bp;
                *(uint2*)&Bh[bi] = make_uint2(h0, h1);
                *(uint2*)&Bl[bi] = make_uint2(q0, q1);
            }
        }
        __syncthreads();

        bf16x8 vbh[4], vbl[4];
        #pragma unroll
        for (int fn = 0; fn < 4; fn++) {
            int br = wn * 64 + fn * 16 + l15;
            int bi = br * 16 + ((quad ^ swz(br)) * 4);
            vbh[fn] = *(const bf16x8*)&Bh[bi];
            vbl[fn] = *(const bf16x8*)&Bl[bi];
        }
        #pragma unroll
        for (int fm = 0; fm < 4; fm++) {
            int arow = wm * 64 + fm * 16 + l15;
            int ai = arow * 16 + ((quad ^ swz(arow)) * 4);
            bf16x8 vah = *(const bf16x8*)&Ah[ai];
            bf16x8 val = *(const bf16x8*)&Al[ai];
            #pragma unroll
            for (int fn = 0; fn < 4; fn++) {
                acc[fm][fn] = __builtin_amdgcn_mfma_f32_16x16x32_bf16(vbh[fn], vah, acc[fm][fn], 0, 0, 0);
                acc[fm][fn] = __builtin_amdgcn_mfma_f32_16x16x32_bf16(vbl[fn], vah, acc[fm][fn], 0, 0, 0);
                acc[fm][fn] = __builtin_amdgcn_mfma_f32_16x16x32_bf16(vbh[fn], val, acc[fm][fn], 0, 0, 0);
            }
        }
    }

    #pragma unroll
    for (int fm = 0; fm < 4; fm++) {
        int row = m0 + wm * 64 + fm * 16 + l15;
        #pragma unroll
        for (int fn = 0; fn < 4; fn++) {
            int colb = n0 + wn * 64 + fn * 16 + quad * 4;
            floatx4 a = acc[fm][fn];
            if (is_qv) {
                if (colb < 1024) {
                    uint32_t h0, l0, h1, l1;
                    split2(a[0], a[1], h0, l0);
                    split2(a[2], a[3], h1, l1);
                    size_t wi = (size_t)row * 512 + (colb >> 1);
                    *(uint2*)&qh[wi] = make_uint2(h0, h1);
                    *(uint2*)&ql[wi] = make_uint2(l0, l1);
                } else {
                    // V transposed: vt[h][d][token] bf16
                    int hh = (colb - 1024) >> 6;
                    int d0 = (colb - 1024) & 63;
                    #pragma unroll
                    for (int j = 0; j < 4; j++)
                        vt[(size_t)(hh * 64 + d0 + j) * 4096 + row] = bf16_rne1(a[j]);
                }
            } else {
                // K pre-scaled by KSCALE (softmax scale * log2e folded in)
                uint32_t h0, l0, h1, l1;
                split2(a[0] * KSCALE, a[1] * KSCALE, h0, l0);
                split2(a[2] * KSCALE, a[3] * KSCALE, h1, l1);
                size_t wi = (size_t)row * 512 + (colb >> 1);
                *(uint2*)&kh[wi] = make_uint2(h0, h1);
                *(uint2*)&kl[wi] = make_uint2(l0, l1);
            }
        }
    }
}

// ---------------- proj GEMM: fused split-K=2, 512 threads, LDS combine ------
// 256 blocks, 1/CU. Waves 0-3 compute k[0,512), waves 4-7 k[512,1024) on the
// same 128x128 output tile; crew1 passes its partial through padded LDS and
// crew0 adds partial+bias and stores. No add_partial launch, no p1 HBM trip.
__global__ __launch_bounds__(512, 2)
void gemm_projF(const uint32_t* __restrict__ Ahg, const uint32_t* __restrict__ Alg,
                const float* __restrict__ Bf, const float* __restrict__ bias,
                float* __restrict__ Cf)
{
    __shared__ uint32_t Ah[2][128 * 16], Al[2][128 * 16];
    __shared__ uint32_t Bh[2][128 * 16], Bl[2][128 * 16];
    __shared__ float    Xc[128 * 132];          // partial exchange, padded

    const int t    = threadIdx.x;
    const int tl   = t & 255;                   // crew-local thread
    const int kz   = t >> 8;                    // crew id (K-half)
    const int lane = t & 63;
    const int w4   = (t >> 6) & 3;              // crew-local wave
    const int wm   = w4 & 1, wn = w4 >> 1;
    const int quad = lane >> 4, l15 = lane & 15;
    const int m0 = blockIdx.y * 128, n0 = blockIdx.x * 128;
    const int k0 = kz * 512;
    const int N  = 1024;

    const int bc  = (tl & 31) * 4;
    const int bk  = (tl >> 5) * 4;
    const int bb  = bk >> 3;
    const int bp  = (bk & 7) >> 1;
    const int nsel = (bc >> 4) & 1;

    floatx4 acc[4][4];
    #pragma unroll
    for (int i = 0; i < 4; i++)
        #pragma unroll
        for (int j = 0; j < 4; j++)
            #pragma unroll
            for (int e = 0; e < 4; e++) acc[i][j][e] = 0.0f;

    for (int kk = 0; kk < 512; kk += 32) {
        const int kg = k0 + kk;
        if (kk) __syncthreads();
        // ---- A staging: pre-split bf16 pairs, straight copy + swizzle ----
        #pragma unroll
        for (int i = 0; i < 2; i++) {
            int idx = tl + i * 256;
            int row = idx >> 2, kbl = idx & 3;
            size_t src = (size_t)(m0 + row) * 512 + (kg >> 1) + kbl * 4;
            int dst = row * 16 + ((kbl ^ swz(row)) * 4);
            *(uint4*)&Ah[kz][dst] = *(const uint4*)&Ahg[src];
            *(uint4*)&Al[kz][dst] = *(const uint4*)&Alg[src];
        }
        // ---- B staging: fp32 -> split bf16 (conflict-min store order) ----
        {
            float4 g4[4];
            #pragma unroll
            for (int j = 0; j < 4; j++)
                g4[j] = *(const float4*)&Bf[(size_t)(kg + bk + j) * N + n0 + bc];
            #pragma unroll
            for (int i = 0; i < 4; i++) {
                int nn = i ^ nsel;
                int n = bc + nn;
                float e0 = ((const float*)&g4[0])[nn];
                float e1 = ((const float*)&g4[1])[nn];
                float e2 = ((const float*)&g4[2])[nn];
                float e3 = ((const float*)&g4[3])[nn];
                uint32_t h0, q0, h1, q1;
                split2(e0, e1, h0, q0);
                split2(e2, e3, h1, q1);
                int bi = n * 16 + ((bb ^ swz(n)) * 4) + bp;
                *(uint2*)&Bh[kz][bi] = make_uint2(h0, h1);
                *(uint2*)&Bl[kz][bi] = make_uint2(q0, q1);
            }
        }
        __syncthreads();

        bf16x8 vbh[4], vbl[4];
        #pragma unroll
        for (int fn = 0; fn < 4; fn++) {
            int br = wn * 64 + fn * 16 + l15;
            int bi = br * 16 + ((quad ^ swz(br)) * 4);
            vbh[fn] = *(const bf16x8*)&Bh[kz][bi];
            vbl[fn] = *(const bf16x8*)&Bl[kz][bi];
        }
        #pragma unroll
        for (int fm = 0; fm < 4; fm++) {
            int arow = wm * 64 + fm * 16 + l15;
            int ai = arow * 16 + ((quad ^ swz(arow)) * 4);
            bf16x8 vah = *(const bf16x8*)&Ah[kz][ai];
            bf16x8 val = *(const bf16x8*)&Al[kz][ai];
            #pragma unroll
            for (int fn = 0; fn < 4; fn++) {
                acc[fm][fn] = __builtin_amdgcn_mfma_f32_16x16x32_bf16(vbh[fn], vah, acc[fm][fn], 0, 0, 0);
                acc[fm][fn] = __builtin_amdgcn_mfma_f32_16x16x32_bf16(vbl[fn], vah, acc[fm][fn], 0, 0, 0);
                acc[fm][fn] = __builtin_amdgcn_mfma_f32_16x16x32_bf16(vbh[fn], val, acc[fm][fn], 0, 0, 0);
            }
        }
    }

    // ---- combine: crew1 -> LDS, crew0 adds partial + bias, stores ----
    __syncthreads();
    if (kz == 1) {
        #pragma unroll
        for (int fm = 0; fm < 4; fm++) {
            int row = wm * 64 + fm * 16 + l15;
            #pragma unroll
            for (int fn = 0; fn < 4; fn++) {
                int col = wn * 64 + fn * 16 + quad * 4;
                floatx4 a = acc[fm][fn];
                float4 v; v.x = a[0]; v.y = a[1]; v.z = a[2]; v.w = a[3];
                *(float4*)&Xc[row * 132 + col] = v;
            }
        }
    }
    __syncthreads();
    if (kz == 0) {
        #pragma unroll
        for (int fm = 0; fm < 4; fm++) {
            int rowl = wm * 64 + fm * 16 + l15;
            int row  = m0 + rowl;
            #pragma unroll
            for (int fn = 0; fn < 4; fn++) {
                int coll = wn * 64 + fn * 16 + quad * 4;
                int colb = n0 + coll;
                floatx4 a = acc[fm][fn];
                float4 p = *(const float4*)&Xc[rowl * 132 + coll];
                float4 bb4 = *(const float4*)&bias[colb];
                float4 v;
                v.x = a[0] + p.x + bb4.x; v.y = a[1] + p.y + bb4.y;
                v.z = a[2] + p.z + bb4.z; v.w = a[3] + p.w + bb4.w;
                *(float4*)&Cf[(size_t)row * N + colb] = v;
            }
        }
    }
}

// ---------------- MFMA flash attention (Q hoisted to registers) -------------
#define FST 34
__global__ __launch_bounds__(256, 2)
void flash_attn(const uint32_t* __restrict__ qhg, const uint32_t* __restrict__ qlg,
                const uint32_t* __restrict__ khg, const uint32_t* __restrict__ klg,
                const uint32_t* __restrict__ vtg,
                uint32_t* __restrict__ xhg, uint32_t* __restrict__ xlg)
{
    __shared__ uint32_t Kh[64 * FST],  Kl[64 * FST];
    __shared__ uint32_t Vt[64 * FST];
    __shared__ uint32_t Pt[128 * FST];

    const int t    = threadIdx.x;
    const int lane = t & 63;
    const int w    = t >> 6;
    const int quad = lane >> 4, l15 = lane & 15;
    const int qb = blockIdx.x;
    const int h  = blockIdx.y;
    const int b  = blockIdx.z;

    const size_t rowbase = (size_t)b * SEQ;

    // ---- Q fragments: load once from global, keep in registers ----
    // (constant across all 32 kt iterations; was 8 ds_read_b128/iter/wave)
    bf16x8 vqh[2][2], vql[2][2];     // [s][nf]
    {
        #pragma unroll
        for (int nf = 0; nf < 2; nf++) {
            size_t row = rowbase + qb * 128 + w * 32 + nf * 16 + l15;
            size_t gw = row * 512 + h * 32 + quad * 4;
            #pragma unroll
            for (int s = 0; s < 2; s++) {
                vqh[s][nf] = *(const bf16x8*)&qhg[gw + s * 16];
                vql[s][nf] = *(const bf16x8*)&qlg[gw + s * 16];
            }
        }
    }

    // ---- prefetch coords + tile kt=0 ----
    const int krow = t >> 2, kc0 = (t & 3) * 8;
    const int vd = t >> 2, vc = t & 3;
    const size_t vrow = (size_t)(h * 64 + vd) * 2048 + (rowbase >> 1);
    uint4 pkh0, pkh1, pkl0, pkl1;
    uint4 pv0, pv1;
    {
        size_t gw = (rowbase + krow) * 512 + h * 32 + kc0;
        pkh0 = *(const uint4*)&khg[gw];
        pkh1 = *(const uint4*)&khg[gw + 4];
        pkl0 = *(const uint4*)&klg[gw];
        pkl1 = *(const uint4*)&klg[gw + 4];
        size_t vw = vrow + vc * 8;
        pv0 = *(const uint4*)&vtg[vw];
        pv1 = *(const uint4*)&vtg[vw + 4];
    }

    float m_i[2] = {-INFINITY, -INFINITY};
    float l_i[2] = {0.0f, 0.0f};
    floatx4 acc_o[2][4];
    #pragma unroll
    for (int nf = 0; nf < 2; nf++)
        #pragma unroll
        for (int fm = 0; fm < 4; fm++)
            #pragma unroll
            for (int e = 0; e < 4; e++) acc_o[nf][fm][e] = 0.0f;

    for (int kt = 0; kt < SEQ / 64; kt++) {
        __syncthreads();
        // ---- stage K from registers ----
        *(uint4*)&Kh[krow * FST + kc0]     = pkh0;
        *(uint4*)&Kh[krow * FST + kc0 + 4] = pkh1;
        *(uint4*)&Kl[krow * FST + kc0]     = pkl0;
        *(uint4*)&Kl[krow * FST + kc0 + 4] = pkl1;
        // ---- stage V^T from registers (pure copy) ----
        {
            int vb0 = vd * FST + vc * 8;
            *(uint2*)&Vt[vb0]     = make_uint2(pv0.x, pv0.y);
            *(uint2*)&Vt[vb0 + 2] = make_uint2(pv0.z, pv0.w);
            *(uint2*)&Vt[vb0 + 4] = make_uint2(pv1.x, pv1.y);
            *(uint2*)&Vt[vb0 + 6] = make_uint2(pv1.z, pv1.w);
        }
        __syncthreads();

        // ---- prefetch tile kt+1 (completes during compute) ----
        if (kt + 1 < SEQ / 64) {
            size_t gw = (rowbase + (kt + 1) * 64 + krow) * 512 + h * 32 + kc0;
            pkh0 = *(const uint4*)&khg[gw];
            pkh1 = *(const uint4*)&khg[gw + 4];
            pkl0 = *(const uint4*)&klg[gw];
            pkl1 = *(const uint4*)&klg[gw + 4];
            size_t vw = vrow + (kt + 1) * 32 + vc * 8;
            pv0 = *(const uint4*)&vtg[vw];
            pv1 = *(const uint4*)&vtg[vw + 4];
        }

        // ---- S^T = K·Q^T (bf16x3); K carries scale*log2e already ----
        floatx4 sacc[2][4];
        #pragma unroll
        for (int nf = 0; nf < 2; nf++)
            #pragma unroll
            for (int fm = 0; fm < 4; fm++)
                #pragma unroll
                for (int e = 0; e < 4; e++) sacc[nf][fm][e] = 0.0f;

        __builtin_amdgcn_s_setprio(1);
        #pragma unroll
        for (int s = 0; s < 2; s++) {
            #pragma unroll
            for (int fm = 0; fm < 4; fm++) {
                int ki = (fm * 16 + l15) * FST + s * 16 + quad * 4;
                bf16x8 vkh = *(const bf16x8*)&Kh[ki];
                bf16x8 vkl = *(const bf16x8*)&Kl[ki];
                #pragma unroll
                for (int nf = 0; nf < 2; nf++) {
                    sacc[nf][fm] = __builtin_amdgcn_mfma_f32_16x16x32_bf16(vkh, vqh[s][nf], sacc[nf][fm], 0, 0, 0);
                    sacc[nf][fm] = __builtin_amdgcn_mfma_f32_16x16x32_bf16(vkh, vql[s][nf], sacc[nf][fm], 0, 0, 0);
                    sacc[nf][fm] = __builtin_amdgcn_mfma_f32_16x16x32_bf16(vkl, vqh[s][nf], sacc[nf][fm], 0, 0, 0);
                }
            }
        }
        __builtin_amdgcn_s_setprio(0);

        // ---- online softmax (base-2 domain, raw v_exp_f32) ----
        #pragma unroll
        for (int nf = 0; nf < 2; nf++) {
            float p[4][4];
            float mt = -INFINITY;
            #pragma unroll
            for (int fm = 0; fm < 4; fm++)
                #pragma unroll
                for (int r = 0; r < 4; r++) {
                    p[fm][r] = sacc[nf][fm][r];
                    mt = fmaxf(mt, p[fm][r]);
                }
            mt = fmaxf(mt, __shfl_xor(mt, 16));
            mt = fmaxf(mt, __shfl_xor(mt, 32));
            float m_new = fmaxf(m_i[nf], mt);
            float alpha = EXP2(m_i[nf] - m_new);
            float rs = 0.0f;
            #pragma unroll
            for (int fm = 0; fm < 4; fm++)
                #pragma unroll
                for (int r = 0; r < 4; r++) {
                    p[fm][r] = EXP2(p[fm][r] - m_new);
                    rs += p[fm][r];
                }
            rs += __shfl_xor(rs, 16);
            rs += __shfl_xor(rs, 32);
            l_i[nf] = l_i[nf] * alpha + rs;
            m_i[nf] = m_new;
            #pragma unroll
            for (int fm = 0; fm < 4; fm++)
                #pragma unroll
                for (int e = 0; e < 4; e++) acc_o[nf][fm][e] *= alpha;

            int qrow = w * 32 + nf * 16 + l15;
            #pragma unroll
            for (int fm = 0; fm < 4; fm++) {
                uint32_t u0 = pack_bf16_rne(p[fm][0], p[fm][1]);
                uint32_t u1 = pack_bf16_rne(p[fm][2], p[fm][3]);
                *(uint2*)&Pt[qrow * FST + fm * 8 + quad * 2] = make_uint2(u0, u1);
            }
        }

        // ---- O^T += Vt · P^T ----
        __builtin_amdgcn_s_setprio(1);
        #pragma unroll
        for (int s = 0; s < 2; s++) {
            bf16x8 pb[2];
            #pragma unroll
            for (int nf = 0; nf < 2; nf++)
                pb[nf] = *(const bf16x8*)&Pt[(w * 32 + nf * 16 + l15) * FST + s * 16 + quad * 4];
            #pragma unroll
            for (int fm = 0; fm < 4; fm++) {
                bf16x8 va = *(const bf16x8*)&Vt[(fm * 16 + l15) * FST + s * 16 + quad * 4];
                #pragma unroll
                for (int nf = 0; nf < 2; nf++)
                    acc_o[nf][fm] = __builtin_amdgcn_mfma_f32_16x16x32_bf16(va, pb[nf], acc_o[nf][fm], 0, 0, 0);
            }
        }
        __builtin_amdgcn_s_setprio(0);
    }

    // ---- epilogue: write x pre-split bf16 ----
    #pragma unroll
    for (int nf = 0; nf < 2; nf++) {
        float rl = 1.0f / l_i[nf];
        size_t row = rowbase + qb * 128 + w * 32 + nf * 16 + l15;
        #pragma unroll
        for (int fm = 0; fm < 4; fm++) {
            int d0 = fm * 16 + quad * 4;
            uint32_t h0, l0, h1, l1;
            split2(acc_o[nf][fm][0] * rl, acc_o[nf][fm][1] * rl, h0, l0);
            split2(acc_o[nf][fm][2] * rl, acc_o[nf][fm][3] * rl, h1, l1);
            size_t wi = row * 512 + ((h * 64 + d0) >> 1);
            *(uint2*)&xhg[wi] = make_uint2(h0, h1);
            *(uint2*)&xlg[wi] = make_uint2(l0, l1);
        }
    }
}

extern "C" void kernel_launch(void* const* d_in, const int* in_sizes, int n_in,
                              void* d_out, int out_size, void* d_ws, size_t ws_size,
                              hipStream_t stream)
{
    const float* input_qv = (const float*)d_in[0];
    const float* input_k  = (const float*)d_in[1];
    const float* W_qv     = (const float*)d_in[2];
    const float* W_k      = (const float*)d_in[3];
    const float* W_proj   = (const float*)d_in[4];
    const float* b_proj   = (const float*)d_in[5];
    float* out = (float*)d_out;

    const size_t RW = 4096 * 512;            // words per [4096][1024-bf16] buffer
    uint32_t* qh = (uint32_t*)d_ws;          // 5 RW = 41.9 MB total
    uint32_t* ql = qh + RW;
    uint32_t* vt = ql + RW;                  // V^T [16 h][64 d][4096 tok] bf16 = 1 RW
    uint32_t* xh = vt + RW;
    uint32_t* xl = xh + RW;
    uint32_t* kh = (uint32_t*)d_out;         // split K parked in d_out (16.8 MB);
    uint32_t* kl = kh + RW;                  // proj GEMM rewrites out afterwards

    dim3 blk(256);
    // fused qv+k projections: 768 blocks = exactly 3/CU
    gemm_qvk<<<dim3(24, 32), blk, 0, stream>>>(
        input_qv, input_k, W_qv, W_k, qh, ql, (ushort*)vt, kh, kl);
    // flash attention (Q in registers; register K/V prefetch; raw v_exp_f32)
    flash_attn<<<dim3(SEQ / 128, NH, BATCH), blk, 0, stream>>>(
        qh, ql, kh, kl, vt, xh, xl);
    // output projection + bias: fused split-K=2, single dispatch
    gemm_projF<<<dim3(8, 32), dim3(512), 0, stream>>>(
        xh, xl, W_proj, b_proj, out);
}

// Round 4
// 316.512 us; speedup vs baseline: 1.2529x; 1.2529x over previous
//
#include <hip/hip_runtime.h>
#include <stdint.h>

#define BATCH 2
#define SEQ   2048
#define DIM   1024
#define NH    16
#define DH    64

typedef short bf16x8 __attribute__((ext_vector_type(8)));
typedef float floatx4 __attribute__((ext_vector_type(4)));

__device__ __forceinline__ int swz(int r) { return (r ^ (r >> 2)) & 3; }

// fast 2^x: raw v_exp_f32
#if __has_builtin(__builtin_amdgcn_exp2f)
#define EXP2(x) __builtin_amdgcn_exp2f(x)
#else
#define EXP2(x) __expf((x) * 0.6931471805599453f)
#endif

// Split two fp32 into packed bf16 hi-pair and lo-pair (truncation split)
__device__ __forceinline__ void split2(float x0, float x1, uint32_t& hi, uint32_t& lo) {
    uint32_t u0 = __float_as_uint(x0), u1 = __float_as_uint(x1);
    uint32_t m0 = u0 & 0xFFFF0000u;
    uint32_t m1 = u1 & 0xFFFF0000u;
    hi = (u0 >> 16) | m1;
    float l0 = x0 - __uint_as_float(m0);
    float l1 = x1 - __uint_as_float(m1);
    lo = (__float_as_uint(l0) >> 16) | (__float_as_uint(l1) & 0xFFFF0000u);
}

__device__ __forceinline__ uint32_t pack_bf16_rne(float x0, float x1) {
    uint32_t u0 = __float_as_uint(x0), u1 = __float_as_uint(x1);
    u0 += 0x7FFFu + ((u0 >> 16) & 1);
    u1 += 0x7FFFu + ((u1 >> 16) & 1);
    return (u0 >> 16) | (u1 & 0xFFFF0000u);
}

__device__ __forceinline__ ushort bf16_rne1(float x) {
    uint32_t u = __float_as_uint(x);
    u += 0x7FFFu + ((u >> 16) & 1);
    return (ushort)(u >> 16);
}

// softmax scale folded into K: 0.125 * log2(e) -> flash uses exp2
#define KSCALE 0.18033688011112042f

// ---------------- fused qv+k projection GEMM -------------------------------
// B-staging store order permuted per-lane (nn = i ^ nsel) so bank bit 4
// (n&1) varies WITHIN each ds_write -> 4 words/bank (structural minimum).
// CRITICAL: value extraction uses STATIC indices + cndmask select; a
// lane-varying register index demotes g4 to scratch (R3: +300MB HBM).
__global__ __launch_bounds__(256, 3)
void gemm_qvk(const float* __restrict__ Aqv, const float* __restrict__ Akp,
              const float* __restrict__ Wqv, const float* __restrict__ Wkp,
              uint32_t* __restrict__ qh, uint32_t* __restrict__ ql,
              ushort* __restrict__ vt,
              uint32_t* __restrict__ kh, uint32_t* __restrict__ kl)
{
    __shared__ uint32_t Ah[128 * 16], Al[128 * 16], Bh[128 * 16], Bl[128 * 16];

    const int t    = threadIdx.x;
    const int lane = t & 63;
    const int w    = t >> 6;
    const int wm   = w & 1, wn = w >> 1;
    const int quad = lane >> 4, l15 = lane & 15;
    const int bx   = blockIdx.x;
    const bool is_qv = (bx < 16);
    const float* Af = is_qv ? Aqv : Akp;
    const float* Bf = is_qv ? Wqv : Wkp;
    const int N    = is_qv ? 2048 : 1024;
    const int n0   = (is_qv ? bx : bx - 16) * 128;
    const int m0   = blockIdx.y * 128;

    const int ar  = t >> 1;
    const int ab0 = (t & 1) * 2;
    const int as  = swz(ar);
    const int bc  = (t & 31) * 4;
    const int bk  = (t >> 5) * 4;
    const int bb  = bk >> 3;
    const int bp  = (bk & 7) >> 1;
    const bool nsel = ((bc >> 4) & 1) != 0;   // lane-varying store-order selector

    floatx4 acc[4][4];
    #pragma unroll
    for (int i = 0; i < 4; i++)
        #pragma unroll
        for (int j = 0; j < 4; j++)
            #pragma unroll
            for (int e = 0; e < 4; e++) acc[i][j][e] = 0.0f;

    for (int k0 = 0; k0 < 1024; k0 += 32) {
        if (k0) __syncthreads();
        {
            float f[16];
            #pragma unroll
            for (int i = 0; i < 4; i++)
                *(float4*)&f[i * 4] =
                    *(const float4*)&Af[(size_t)(m0 + ar) * 1024 + k0 + ab0 * 8 + i * 4];
            uint32_t hi[8], lo[8];
            #pragma unroll
            for (int j = 0; j < 8; j++) split2(f[2 * j], f[2 * j + 1], hi[j], lo[j]);
            int i0 = ar * 16 + ((ab0 ^ as) * 4);
            int i1 = ar * 16 + (((ab0 + 1) ^ as) * 4);
            *(uint4*)&Ah[i0] = make_uint4(hi[0], hi[1], hi[2], hi[3]);
            *(uint4*)&Ah[i1] = make_uint4(hi[4], hi[5], hi[6], hi[7]);
            *(uint4*)&Al[i0] = make_uint4(lo[0], lo[1], lo[2], lo[3]);
            *(uint4*)&Al[i1] = make_uint4(lo[4], lo[5], lo[6], lo[7]);
        }
        {
            float4 g4[4];
            #pragma unroll
            for (int j = 0; j < 4; j++)
                g4[j] = *(const float4*)&Bf[(size_t)(k0 + bk + j) * N + n0 + bc];
            #pragma unroll
            for (int i = 0; i < 4; i++) {
                int n = bc + (i ^ (nsel ? 1 : 0));
                // static extracts (i, i^1 are literals after unroll) + select
                float e0 = nsel ? ((const float*)&g4[0])[i ^ 1] : ((const float*)&g4[0])[i];
                float e1 = nsel ? ((const float*)&g4[1])[i ^ 1] : ((const float*)&g4[1])[i];
                float e2 = nsel ? ((const float*)&g4[2])[i ^ 1] : ((const float*)&g4[2])[i];
                float e3 = nsel ? ((const float*)&g4[3])[i ^ 1] : ((const float*)&g4[3])[i];
                uint32_t h0, q0, h1, q1;
                split2(e0, e1, h0, q0);
                split2(e2, e3, h1, q1);
                int bi = n * 16 + ((bb ^ swz(n)) * 4) + bp;
                *(uint2*)&Bh[bi] = make_uint2(h0, h1);
                *(uint2*)&Bl[bi] = make_uint2(q0, q1);
            }
        }
        __syncthreads();

        bf16x8 vbh[4], vbl[4];
        #pragma unroll
        for (int fn = 0; fn < 4; fn++) {
            int br = wn * 64 + fn * 16 + l15;
            int bi = br * 16 + ((quad ^ swz(br)) * 4);
            vbh[fn] = *(const bf16x8*)&Bh[bi];
            vbl[fn] = *(const bf16x8*)&Bl[bi];
        }
        #pragma unroll
        for (int fm = 0; fm < 4; fm++) {
            int arow = wm * 64 + fm * 16 + l15;
            int ai = arow * 16 + ((quad ^ swz(arow)) * 4);
            bf16x8 vah = *(const bf16x8*)&Ah[ai];
            bf16x8 val = *(const bf16x8*)&Al[ai];
            #pragma unroll
            for (int fn = 0; fn < 4; fn++) {
                acc[fm][fn] = __builtin_amdgcn_mfma_f32_16x16x32_bf16(vbh[fn], vah, acc[fm][fn], 0, 0, 0);
                acc[fm][fn] = __builtin_amdgcn_mfma_f32_16x16x32_bf16(vbl[fn], vah, acc[fm][fn], 0, 0, 0);
                acc[fm][fn] = __builtin_amdgcn_mfma_f32_16x16x32_bf16(vbh[fn], val, acc[fm][fn], 0, 0, 0);
            }
        }
    }

    #pragma unroll
    for (int fm = 0; fm < 4; fm++) {
        int row = m0 + wm * 64 + fm * 16 + l15;
        #pragma unroll
        for (int fn = 0; fn < 4; fn++) {
            int colb = n0 + wn * 64 + fn * 16 + quad * 4;
            floatx4 a = acc[fm][fn];
            if (is_qv) {
                if (colb < 1024) {
                    uint32_t h0, l0, h1, l1;
                    split2(a[0], a[1], h0, l0);
                    split2(a[2], a[3], h1, l1);
                    size_t wi = (size_t)row * 512 + (colb >> 1);
                    *(uint2*)&qh[wi] = make_uint2(h0, h1);
                    *(uint2*)&ql[wi] = make_uint2(l0, l1);
                } else {
                    // V transposed: vt[h][d][token] bf16
                    int hh = (colb - 1024) >> 6;
                    int d0 = (colb - 1024) & 63;
                    #pragma unroll
                    for (int j = 0; j < 4; j++)
                        vt[(size_t)(hh * 64 + d0 + j) * 4096 + row] = bf16_rne1(a[j]);
                }
            } else {
                // K pre-scaled by KSCALE (softmax scale * log2e folded in)
                uint32_t h0, l0, h1, l1;
                split2(a[0] * KSCALE, a[1] * KSCALE, h0, l0);
                split2(a[2] * KSCALE, a[3] * KSCALE, h1, l1);
                size_t wi = (size_t)row * 512 + (colb >> 1);
                *(uint2*)&kh[wi] = make_uint2(h0, h1);
                *(uint2*)&kl[wi] = make_uint2(l0, l1);
            }
        }
    }
}

// ---------------- proj GEMM: fused split-K=2, 512 threads, LDS combine ------
// 256 blocks, 1/CU (8 waves/CU, same as 2x 256-thread blocks). Waves 0-3
// compute k[0,512), waves 4-7 k[512,1024); crew1 passes partial through
// padded LDS; crew0 adds partial+bias, stores. No extra launch, no p1 trip.
__global__ __launch_bounds__(512, 2)
void gemm_projF(const uint32_t* __restrict__ Ahg, const uint32_t* __restrict__ Alg,
                const float* __restrict__ Bf, const float* __restrict__ bias,
                float* __restrict__ Cf)
{
    __shared__ uint32_t Ah[2][128 * 16], Al[2][128 * 16];
    __shared__ uint32_t Bh[2][128 * 16], Bl[2][128 * 16];
    __shared__ float    Xc[128 * 132];          // partial exchange, padded

    const int t    = threadIdx.x;
    const int tl   = t & 255;                   // crew-local thread
    const int kz   = t >> 8;                    // crew id (K-half)
    const int lane = t & 63;
    const int w4   = (t >> 6) & 3;              // crew-local wave
    const int wm   = w4 & 1, wn = w4 >> 1;
    const int quad = lane >> 4, l15 = lane & 15;
    const int m0 = blockIdx.y * 128, n0 = blockIdx.x * 128;
    const int k0 = kz * 512;
    const int N  = 1024;

    const int bc  = (tl & 31) * 4;
    const int bk  = (tl >> 5) * 4;
    const int bb  = bk >> 3;
    const int bp  = (bk & 7) >> 1;
    const bool nsel = ((bc >> 4) & 1) != 0;

    floatx4 acc[4][4];
    #pragma unroll
    for (int i = 0; i < 4; i++)
        #pragma unroll
        for (int j = 0; j < 4; j++)
            #pragma unroll
            for (int e = 0; e < 4; e++) acc[i][j][e] = 0.0f;

    for (int kk = 0; kk < 512; kk += 32) {
        const int kg = k0 + kk;
        if (kk) __syncthreads();
        // ---- A staging: pre-split bf16 pairs, straight copy + swizzle ----
        #pragma unroll
        for (int i = 0; i < 2; i++) {
            int idx = tl + i * 256;
            int row = idx >> 2, kbl = idx & 3;
            size_t src = (size_t)(m0 + row) * 512 + (kg >> 1) + kbl * 4;
            int dst = row * 16 + ((kbl ^ swz(row)) * 4);
            *(uint4*)&Ah[kz][dst] = *(const uint4*)&Ahg[src];
            *(uint4*)&Al[kz][dst] = *(const uint4*)&Alg[src];
        }
        // ---- B staging: fp32 -> split bf16 (conflict-min, static extracts) --
        {
            float4 g4[4];
            #pragma unroll
            for (int j = 0; j < 4; j++)
                g4[j] = *(const float4*)&Bf[(size_t)(kg + bk + j) * N + n0 + bc];
            #pragma unroll
            for (int i = 0; i < 4; i++) {
                int n = bc + (i ^ (nsel ? 1 : 0));
                float e0 = nsel ? ((const float*)&g4[0])[i ^ 1] : ((const float*)&g4[0])[i];
                float e1 = nsel ? ((const float*)&g4[1])[i ^ 1] : ((const float*)&g4[1])[i];
                float e2 = nsel ? ((const float*)&g4[2])[i ^ 1] : ((const float*)&g4[2])[i];
                float e3 = nsel ? ((const float*)&g4[3])[i ^ 1] : ((const float*)&g4[3])[i];
                uint32_t h0, q0, h1, q1;
                split2(e0, e1, h0, q0);
                split2(e2, e3, h1, q1);
                int bi = n * 16 + ((bb ^ swz(n)) * 4) + bp;
                *(uint2*)&Bh[kz][bi] = make_uint2(h0, h1);
                *(uint2*)&Bl[kz][bi] = make_uint2(q0, q1);
            }
        }
        __syncthreads();

        bf16x8 vbh[4], vbl[4];
        #pragma unroll
        for (int fn = 0; fn < 4; fn++) {
            int br = wn * 64 + fn * 16 + l15;
            int bi = br * 16 + ((quad ^ swz(br)) * 4);
            vbh[fn] = *(const bf16x8*)&Bh[kz][bi];
            vbl[fn] = *(const bf16x8*)&Bl[kz][bi];
        }
        #pragma unroll
        for (int fm = 0; fm < 4; fm++) {
            int arow = wm * 64 + fm * 16 + l15;
            int ai = arow * 16 + ((quad ^ swz(arow)) * 4);
            bf16x8 vah = *(const bf16x8*)&Ah[kz][ai];
            bf16x8 val = *(const bf16x8*)&Al[kz][ai];
            #pragma unroll
            for (int fn = 0; fn < 4; fn++) {
                acc[fm][fn] = __builtin_amdgcn_mfma_f32_16x16x32_bf16(vbh[fn], vah, acc[fm][fn], 0, 0, 0);
                acc[fm][fn] = __builtin_amdgcn_mfma_f32_16x16x32_bf16(vbl[fn], vah, acc[fm][fn], 0, 0, 0);
                acc[fm][fn] = __builtin_amdgcn_mfma_f32_16x16x32_bf16(vbh[fn], val, acc[fm][fn], 0, 0, 0);
            }
        }
    }

    // ---- combine: crew1 -> LDS, crew0 adds partial + bias, stores ----
    __syncthreads();
    if (kz == 1) {
        #pragma unroll
        for (int fm = 0; fm < 4; fm++) {
            int row = wm * 64 + fm * 16 + l15;
            #pragma unroll
            for (int fn = 0; fn < 4; fn++) {
                int col = wn * 64 + fn * 16 + quad * 4;
                floatx4 a = acc[fm][fn];
                float4 v; v.x = a[0]; v.y = a[1]; v.z = a[2]; v.w = a[3];
                *(float4*)&Xc[row * 132 + col] = v;
            }
        }
    }
    __syncthreads();
    if (kz == 0) {
        #pragma unroll
        for (int fm = 0; fm < 4; fm++) {
            int rowl = wm * 64 + fm * 16 + l15;
            int row  = m0 + rowl;
            #pragma unroll
            for (int fn = 0; fn < 4; fn++) {
                int coll = wn * 64 + fn * 16 + quad * 4;
                int colb = n0 + coll;
                floatx4 a = acc[fm][fn];
                float4 p = *(const float4*)&Xc[rowl * 132 + coll];
                float4 bb4 = *(const float4*)&bias[colb];
                float4 v;
                v.x = a[0] + p.x + bb4.x; v.y = a[1] + p.y + bb4.y;
                v.z = a[2] + p.z + bb4.z; v.w = a[3] + p.w + bb4.w;
                *(float4*)&Cf[(size_t)row * N + colb] = v;
            }
        }
    }
}

// ---------------- MFMA flash attention (Q hoisted to registers) -------------
#define FST 34
__global__ __launch_bounds__(256, 2)
void flash_attn(const uint32_t* __restrict__ qhg, const uint32_t* __restrict__ qlg,
                const uint32_t* __restrict__ khg, const uint32_t* __restrict__ klg,
                const uint32_t* __restrict__ vtg,
                uint32_t* __restrict__ xhg, uint32_t* __restrict__ xlg)
{
    __shared__ uint32_t Kh[64 * FST],  Kl[64 * FST];
    __shared__ uint32_t Vt[64 * FST];
    __shared__ uint32_t Pt[128 * FST];

    const int t    = threadIdx.x;
    const int lane = t & 63;
    const int w    = t >> 6;
    const int quad = lane >> 4, l15 = lane & 15;
    const int qb = blockIdx.x;
    const int h  = blockIdx.y;
    const int b  = blockIdx.z;

    const size_t rowbase = (size_t)b * SEQ;

    // ---- Q fragments: load once from global, keep in registers ----
    // (constant across all 32 kt iterations; was 8 ds_read_b128/iter/wave)
    bf16x8 vqh[2][2], vql[2][2];     // [s][nf]
    {
        #pragma unroll
        for (int nf = 0; nf < 2; nf++) {
            size_t row = rowbase + qb * 128 + w * 32 + nf * 16 + l15;
            size_t gw = row * 512 + h * 32 + quad * 4;
            #pragma unroll
            for (int s = 0; s < 2; s++) {
                vqh[s][nf] = *(const bf16x8*)&qhg[gw + s * 16];
                vql[s][nf] = *(const bf16x8*)&qlg[gw + s * 16];
            }
        }
    }

    // ---- prefetch coords + tile kt=0 ----
    const int krow = t >> 2, kc0 = (t & 3) * 8;
    const int vd = t >> 2, vc = t & 3;
    const size_t vrow = (size_t)(h * 64 + vd) * 2048 + (rowbase >> 1);
    uint4 pkh0, pkh1, pkl0, pkl1;
    uint4 pv0, pv1;
    {
        size_t gw = (rowbase + krow) * 512 + h * 32 + kc0;
        pkh0 = *(const uint4*)&khg[gw];
        pkh1 = *(const uint4*)&khg[gw + 4];
        pkl0 = *(const uint4*)&klg[gw];
        pkl1 = *(const uint4*)&klg[gw + 4];
        size_t vw = vrow + vc * 8;
        pv0 = *(const uint4*)&vtg[vw];
        pv1 = *(const uint4*)&vtg[vw + 4];
    }

    float m_i[2] = {-INFINITY, -INFINITY};
    float l_i[2] = {0.0f, 0.0f};
    floatx4 acc_o[2][4];
    #pragma unroll
    for (int nf = 0; nf < 2; nf++)
        #pragma unroll
        for (int fm = 0; fm < 4; fm++)
            #pragma unroll
            for (int e = 0; e < 4; e++) acc_o[nf][fm][e] = 0.0f;

    for (int kt = 0; kt < SEQ / 64; kt++) {
        __syncthreads();
        // ---- stage K from registers ----
        *(uint4*)&Kh[krow * FST + kc0]     = pkh0;
        *(uint4*)&Kh[krow * FST + kc0 + 4] = pkh1;
        *(uint4*)&Kl[krow * FST + kc0]     = pkl0;
        *(uint4*)&Kl[krow * FST + kc0 + 4] = pkl1;
        // ---- stage V^T from registers (pure copy) ----
        {
            int vb0 = vd * FST + vc * 8;
            *(uint2*)&Vt[vb0]     = make_uint2(pv0.x, pv0.y);
            *(uint2*)&Vt[vb0 + 2] = make_uint2(pv0.z, pv0.w);
            *(uint2*)&Vt[vb0 + 4] = make_uint2(pv1.x, pv1.y);
            *(uint2*)&Vt[vb0 + 6] = make_uint2(pv1.z, pv1.w);
        }
        __syncthreads();

        // ---- prefetch tile kt+1 (completes during compute) ----
        if (kt + 1 < SEQ / 64) {
            size_t gw = (rowbase + (kt + 1) * 64 + krow) * 512 + h * 32 + kc0;
            pkh0 = *(const uint4*)&khg[gw];
            pkh1 = *(const uint4*)&khg[gw + 4];
            pkl0 = *(const uint4*)&klg[gw];
            pkl1 = *(const uint4*)&klg[gw + 4];
            size_t vw = vrow + (kt + 1) * 32 + vc * 8;
            pv0 = *(const uint4*)&vtg[vw];
            pv1 = *(const uint4*)&vtg[vw + 4];
        }

        // ---- S^T = K·Q^T (bf16x3); K carries scale*log2e already ----
        floatx4 sacc[2][4];
        #pragma unroll
        for (int nf = 0; nf < 2; nf++)
            #pragma unroll
            for (int fm = 0; fm < 4; fm++)
                #pragma unroll
                for (int e = 0; e < 4; e++) sacc[nf][fm][e] = 0.0f;

        __builtin_amdgcn_s_setprio(1);
        #pragma unroll
        for (int s = 0; s < 2; s++) {
            #pragma unroll
            for (int fm = 0; fm < 4; fm++) {
                int ki = (fm * 16 + l15) * FST + s * 16 + quad * 4;
                bf16x8 vkh = *(const bf16x8*)&Kh[ki];
                bf16x8 vkl = *(const bf16x8*)&Kl[ki];
                #pragma unroll
                for (int nf = 0; nf < 2; nf++) {
                    sacc[nf][fm] = __builtin_amdgcn_mfma_f32_16x16x32_bf16(vkh, vqh[s][nf], sacc[nf][fm], 0, 0, 0);
                    sacc[nf][fm] = __builtin_amdgcn_mfma_f32_16x16x32_bf16(vkh, vql[s][nf], sacc[nf][fm], 0, 0, 0);
                    sacc[nf][fm] = __builtin_amdgcn_mfma_f32_16x16x32_bf16(vkl, vqh[s][nf], sacc[nf][fm], 0, 0, 0);
                }
            }
        }
        __builtin_amdgcn_s_setprio(0);

        // ---- online softmax (base-2 domain, raw v_exp_f32) ----
        #pragma unroll
        for (int nf = 0; nf < 2; nf++) {
            float p[4][4];
            float mt = -INFINITY;
            #pragma unroll
            for (int fm = 0; fm < 4; fm++)
                #pragma unroll
                for (int r = 0; r < 4; r++) {
                    p[fm][r] = sacc[nf][fm][r];
                    mt = fmaxf(mt, p[fm][r]);
                }
            mt = fmaxf(mt, __shfl_xor(mt, 16));
            mt = fmaxf(mt, __shfl_xor(mt, 32));
            float m_new = fmaxf(m_i[nf], mt);
            float alpha = EXP2(m_i[nf] - m_new);
            float rs = 0.0f;
            #pragma unroll
            for (int fm = 0; fm < 4; fm++)
                #pragma unroll
                for (int r = 0; r < 4; r++) {
                    p[fm][r] = EXP2(p[fm][r] - m_new);
                    rs += p[fm][r];
                }
            rs += __shfl_xor(rs, 16);
            rs += __shfl_xor(rs, 32);
            l_i[nf] = l_i[nf] * alpha + rs;
            m_i[nf] = m_new;
            #pragma unroll
            for (int fm = 0; fm < 4; fm++)
                #pragma unroll
                for (int e = 0; e < 4; e++) acc_o[nf][fm][e] *= alpha;

            int qrow = w * 32 + nf * 16 + l15;
            #pragma unroll
            for (int fm = 0; fm < 4; fm++) {
                uint32_t u0 = pack_bf16_rne(p[fm][0], p[fm][1]);
                uint32_t u1 = pack_bf16_rne(p[fm][2], p[fm][3]);
                *(uint2*)&Pt[qrow * FST + fm * 8 + quad * 2] = make_uint2(u0, u1);
            }
        }

        // ---- O^T += Vt · P^T ----
        __builtin_amdgcn_s_setprio(1);
        #pragma unroll
        for (int s = 0; s < 2; s++) {
            bf16x8 pb[2];
            #pragma unroll
            for (int nf = 0; nf < 2; nf++)
                pb[nf] = *(const bf16x8*)&Pt[(w * 32 + nf * 16 + l15) * FST + s * 16 + quad * 4];
            #pragma unroll
            for (int fm = 0; fm < 4; fm++) {
                bf16x8 va = *(const bf16x8*)&Vt[(fm * 16 + l15) * FST + s * 16 + quad * 4];
                #pragma unroll
                for (int nf = 0; nf < 2; nf++)
                    acc_o[nf][fm] = __builtin_amdgcn_mfma_f32_16x16x32_bf16(va, pb[nf], acc_o[nf][fm], 0, 0, 0);
            }
        }
        __builtin_amdgcn_s_setprio(0);
    }

    // ---- epilogue: write x pre-split bf16 ----
    #pragma unroll
    for (int nf = 0; nf < 2; nf++) {
        float rl = 1.0f / l_i[nf];
        size_t row = rowbase + qb * 128 + w * 32 + nf * 16 + l15;
        #pragma unroll
        for (int fm = 0; fm < 4; fm++) {
            int d0 = fm * 16 + quad * 4;
            uint32_t h0, l0, h1, l1;
            split2(acc_o[nf][fm][0] * rl, acc_o[nf][fm][1] * rl, h0, l0);
            split2(acc_o[nf][fm][2] * rl, acc_o[nf][fm][3] * rl, h1, l1);
            size_t wi = row * 512 + ((h * 64 + d0) >> 1);
            *(uint2*)&xhg[wi] = make_uint2(h0, h1);
            *(uint2*)&xlg[wi] = make_uint2(l0, l1);
        }
    }
}

extern "C" void kernel_launch(void* const* d_in, const int* in_sizes, int n_in,
                              void* d_out, int out_size, void* d_ws, size_t ws_size,
                              hipStream_t stream)
{
    const float* input_qv = (const float*)d_in[0];
    const float* input_k  = (const float*)d_in[1];
    const float* W_qv     = (const float*)d_in[2];
    const float* W_k      = (const float*)d_in[3];
    const float* W_proj   = (const float*)d_in[4];
    const float* b_proj   = (const float*)d_in[5];
    float* out = (float*)d_out;

    const size_t RW = 4096 * 512;            // words per [4096][1024-bf16] buffer
    uint32_t* qh = (uint32_t*)d_ws;          // 5 RW = 41.9 MB total
    uint32_t* ql = qh + RW;
    uint32_t* vt = ql + RW;                  // V^T [16 h][64 d][4096 tok] bf16 = 1 RW
    uint32_t* xh = vt + RW;
    uint32_t* xl = xh + RW;
    uint32_t* kh = (uint32_t*)d_out;         // split K parked in d_out (16.8 MB);
    uint32_t* kl = kh + RW;                  // proj GEMM rewrites out afterwards

    dim3 blk(256);
    // fused qv+k projections: 768 blocks = exactly 3/CU
    gemm_qvk<<<dim3(24, 32), blk, 0, stream>>>(
        input_qv, input_k, W_qv, W_k, qh, ql, (ushort*)vt, kh, kl);
    // flash attention (Q in registers; register K/V prefetch; raw v_exp_f32)
    flash_attn<<<dim3(SEQ / 128, NH, BATCH), blk, 0, stream>>>(
        qh, ql, kh, kl, vt, xh, xl);
    // output projection + bias: fused split-K=2, single dispatch
    gemm_projF<<<dim3(8, 32), dim3(512), 0, stream>>>(
        xh, xl, W_proj, b_proj, out);
}

// Round 5
// 312.361 us; speedup vs baseline: 1.2696x; 1.0133x over previous
//
#include <hip/hip_runtime.h>
#include <stdint.h>

#define BATCH 2
#define SEQ   2048
#define DIM   1024
#define NH    16
#define DH    64

typedef short bf16x8 __attribute__((ext_vector_type(8)));
typedef float floatx4 __attribute__((ext_vector_type(4)));

__device__ __forceinline__ int swz(int r) { return (r ^ (r >> 2)) & 3; }

// fast 2^x: raw v_exp_f32
#if __has_builtin(__builtin_amdgcn_exp2f)
#define EXP2(x) __builtin_amdgcn_exp2f(x)
#else
#define EXP2(x) __expf((x) * 0.6931471805599453f)
#endif

// Split two fp32 into packed bf16 hi-pair and lo-pair (truncation split)
__device__ __forceinline__ void split2(float x0, float x1, uint32_t& hi, uint32_t& lo) {
    uint32_t u0 = __float_as_uint(x0), u1 = __float_as_uint(x1);
    uint32_t m0 = u0 & 0xFFFF0000u;
    uint32_t m1 = u1 & 0xFFFF0000u;
    hi = (u0 >> 16) | m1;
    float l0 = x0 - __uint_as_float(m0);
    float l1 = x1 - __uint_as_float(m1);
    lo = (__float_as_uint(l0) >> 16) | (__float_as_uint(l1) & 0xFFFF0000u);
}

__device__ __forceinline__ uint32_t pack_bf16_rne(float x0, float x1) {
    uint32_t u0 = __float_as_uint(x0), u1 = __float_as_uint(x1);
    u0 += 0x7FFFu + ((u0 >> 16) & 1);
    u1 += 0x7FFFu + ((u1 >> 16) & 1);
    return (u0 >> 16) | (u1 & 0xFFFF0000u);
}

__device__ __forceinline__ ushort bf16_rne1(float x) {
    uint32_t u = __float_as_uint(x);
    u += 0x7FFFu + ((u >> 16) & 1);
    return (ushort)(u >> 16);
}

// softmax scale folded into K: 0.125 * log2(e) -> flash uses exp2
#define KSCALE 0.18033688011112042f

// ---------------- fused qv+k projection GEMM (R4, unchanged) ----------------
__global__ __launch_bounds__(256, 3)
void gemm_qvk(const float* __restrict__ Aqv, const float* __restrict__ Akp,
              const float* __restrict__ Wqv, const float* __restrict__ Wkp,
              uint32_t* __restrict__ qh, uint32_t* __restrict__ ql,
              ushort* __restrict__ vt,
              uint32_t* __restrict__ kh, uint32_t* __restrict__ kl)
{
    __shared__ uint32_t Ah[128 * 16], Al[128 * 16], Bh[128 * 16], Bl[128 * 16];

    const int t    = threadIdx.x;
    const int lane = t & 63;
    const int w    = t >> 6;
    const int wm   = w & 1, wn = w >> 1;
    const int quad = lane >> 4, l15 = lane & 15;
    const int bx   = blockIdx.x;
    const bool is_qv = (bx < 16);
    const float* Af = is_qv ? Aqv : Akp;
    const float* Bf = is_qv ? Wqv : Wkp;
    const int N    = is_qv ? 2048 : 1024;
    const int n0   = (is_qv ? bx : bx - 16) * 128;
    const int m0   = blockIdx.y * 128;

    const int ar  = t >> 1;
    const int ab0 = (t & 1) * 2;
    const int as  = swz(ar);
    const int bc  = (t & 31) * 4;
    const int bk  = (t >> 5) * 4;
    const int bb  = bk >> 3;
    const int bp  = (bk & 7) >> 1;
    const bool nsel = ((bc >> 4) & 1) != 0;   // lane-varying store-order selector

    floatx4 acc[4][4];
    #pragma unroll
    for (int i = 0; i < 4; i++)
        #pragma unroll
        for (int j = 0; j < 4; j++)
            #pragma unroll
            for (int e = 0; e < 4; e++) acc[i][j][e] = 0.0f;

    for (int k0 = 0; k0 < 1024; k0 += 32) {
        if (k0) __syncthreads();
        {
            float f[16];
            #pragma unroll
            for (int i = 0; i < 4; i++)
                *(float4*)&f[i * 4] =
                    *(const float4*)&Af[(size_t)(m0 + ar) * 1024 + k0 + ab0 * 8 + i * 4];
            uint32_t hi[8], lo[8];
            #pragma unroll
            for (int j = 0; j < 8; j++) split2(f[2 * j], f[2 * j + 1], hi[j], lo[j]);
            int i0 = ar * 16 + ((ab0 ^ as) * 4);
            int i1 = ar * 16 + (((ab0 + 1) ^ as) * 4);
            *(uint4*)&Ah[i0] = make_uint4(hi[0], hi[1], hi[2], hi[3]);
            *(uint4*)&Ah[i1] = make_uint4(hi[4], hi[5], hi[6], hi[7]);
            *(uint4*)&Al[i0] = make_uint4(lo[0], lo[1], lo[2], lo[3]);
            *(uint4*)&Al[i1] = make_uint4(lo[4], lo[5], lo[6], lo[7]);
        }
        {
            float4 g4[4];
            #pragma unroll
            for (int j = 0; j < 4; j++)
                g4[j] = *(const float4*)&Bf[(size_t)(k0 + bk + j) * N + n0 + bc];
            #pragma unroll
            for (int i = 0; i < 4; i++) {
                int n = bc + (i ^ (nsel ? 1 : 0));
                // static extracts (i, i^1 are literals after unroll) + select
                float e0 = nsel ? ((const float*)&g4[0])[i ^ 1] : ((const float*)&g4[0])[i];
                float e1 = nsel ? ((const float*)&g4[1])[i ^ 1] : ((const float*)&g4[1])[i];
                float e2 = nsel ? ((const float*)&g4[2])[i ^ 1] : ((const float*)&g4[2])[i];
                float e3 = nsel ? ((const float*)&g4[3])[i ^ 1] : ((const float*)&g4[3])[i];
                uint32_t h0, q0, h1, q1;
                split2(e0, e1, h0, q0);
                split2(e2, e3, h1, q1);
                int bi = n * 16 + ((bb ^ swz(n)) * 4) + bp;
                *(uint2*)&Bh[bi] = make_uint2(h0, h1);
                *(uint2*)&Bl[bi] = make_uint2(q0, q1);
            }
        }
        __syncthreads();

        bf16x8 vbh[4], vbl[4];
        #pragma unroll
        for (int fn = 0; fn < 4; fn++) {
            int br = wn * 64 + fn * 16 + l15;
            int bi = br * 16 + ((quad ^ swz(br)) * 4);
            vbh[fn] = *(const bf16x8*)&Bh[bi];
            vbl[fn] = *(const bf16x8*)&Bl[bi];
        }
        #pragma unroll
        for (int fm = 0; fm < 4; fm++) {
            int arow = wm * 64 + fm * 16 + l15;
            int ai = arow * 16 + ((quad ^ swz(arow)) * 4);
            bf16x8 vah = *(const bf16x8*)&Ah[ai];
            bf16x8 val = *(const bf16x8*)&Al[ai];
            #pragma unroll
            for (int fn = 0; fn < 4; fn++) {
                acc[fm][fn] = __builtin_amdgcn_mfma_f32_16x16x32_bf16(vbh[fn], vah, acc[fm][fn], 0, 0, 0);
                acc[fm][fn] = __builtin_amdgcn_mfma_f32_16x16x32_bf16(vbl[fn], vah, acc[fm][fn], 0, 0, 0);
                acc[fm][fn] = __builtin_amdgcn_mfma_f32_16x16x32_bf16(vbh[fn], val, acc[fm][fn], 0, 0, 0);
            }
        }
    }

    #pragma unroll
    for (int fm = 0; fm < 4; fm++) {
        int row = m0 + wm * 64 + fm * 16 + l15;
        #pragma unroll
        for (int fn = 0; fn < 4; fn++) {
            int colb = n0 + wn * 64 + fn * 16 + quad * 4;
            floatx4 a = acc[fm][fn];
            if (is_qv) {
                if (colb < 1024) {
                    uint32_t h0, l0, h1, l1;
                    split2(a[0], a[1], h0, l0);
                    split2(a[2], a[3], h1, l1);
                    size_t wi = (size_t)row * 512 + (colb >> 1);
                    *(uint2*)&qh[wi] = make_uint2(h0, h1);
                    *(uint2*)&ql[wi] = make_uint2(l0, l1);
                } else {
                    // V transposed: vt[h][d][token] bf16
                    int hh = (colb - 1024) >> 6;
                    int d0 = (colb - 1024) & 63;
                    #pragma unroll
                    for (int j = 0; j < 4; j++)
                        vt[(size_t)(hh * 64 + d0 + j) * 4096 + row] = bf16_rne1(a[j]);
                }
            } else {
                // K pre-scaled by KSCALE (softmax scale * log2e folded in)
                uint32_t h0, l0, h1, l1;
                split2(a[0] * KSCALE, a[1] * KSCALE, h0, l0);
                split2(a[2] * KSCALE, a[3] * KSCALE, h1, l1);
                size_t wi = (size_t)row * 512 + (colb >> 1);
                *(uint2*)&kh[wi] = make_uint2(h0, h1);
                *(uint2*)&kl[wi] = make_uint2(l0, l1);
            }
        }
    }
}

// ---------------- proj GEMM: split-K=2 at 128x128, 32KB LDS, 512 blocks -----
// 2 blocks/CU avg (3/CU-capable by resources) -> inter-block overlap at
// barriers, unlike the 1-block/CU fused variant (R4: ~105us, reverted).
__global__ __launch_bounds__(256, 3)
void gemm_projA(const uint32_t* __restrict__ Ahg, const uint32_t* __restrict__ Alg,
                const float* __restrict__ Bf, const float* __restrict__ bias,
                float* __restrict__ Cf, float* __restrict__ P1)
{
    __shared__ uint32_t Ah[128 * 16], Al[128 * 16], Bh[128 * 16], Bl[128 * 16];

    const int t    = threadIdx.x;
    const int lane = t & 63;
    const int w    = t >> 6;
    const int wm   = w & 1, wn = w >> 1;
    const int quad = lane >> 4, l15 = lane & 15;
    const int m0 = blockIdx.y * 128, n0 = blockIdx.x * 128;
    const int kz = blockIdx.z;
    const int k0 = kz * 512;
    const int N  = 1024;

    const int bc  = (t & 31) * 4;
    const int bk  = (t >> 5) * 4;
    const int bb  = bk >> 3;
    const int bp  = (bk & 7) >> 1;
    const bool nsel = ((bc >> 4) & 1) != 0;

    floatx4 acc[4][4];
    #pragma unroll
    for (int i = 0; i < 4; i++)
        #pragma unroll
        for (int j = 0; j < 4; j++)
            #pragma unroll
            for (int e = 0; e < 4; e++) acc[i][j][e] = 0.0f;

    for (int kk = 0; kk < 512; kk += 32) {
        const int kg = k0 + kk;
        if (kk) __syncthreads();
        // ---- A staging: pre-split bf16 pairs, straight copy + swizzle ----
        #pragma unroll
        for (int i = 0; i < 2; i++) {
            int idx = t + i * 256;
            int row = idx >> 2, kbl = idx & 3;
            size_t src = (size_t)(m0 + row) * 512 + (kg >> 1) + kbl * 4;
            int dst = row * 16 + ((kbl ^ swz(row)) * 4);
            *(uint4*)&Ah[dst] = *(const uint4*)&Ahg[src];
            *(uint4*)&Al[dst] = *(const uint4*)&Alg[src];
        }
        // ---- B staging: fp32 -> split bf16 (conflict-min, static extracts) --
        {
            float4 g4[4];
            #pragma unroll
            for (int j = 0; j < 4; j++)
                g4[j] = *(const float4*)&Bf[(size_t)(kg + bk + j) * N + n0 + bc];
            #pragma unroll
            for (int i = 0; i < 4; i++) {
                int n = bc + (i ^ (nsel ? 1 : 0));
                float e0 = nsel ? ((const float*)&g4[0])[i ^ 1] : ((const float*)&g4[0])[i];
                float e1 = nsel ? ((const float*)&g4[1])[i ^ 1] : ((const float*)&g4[1])[i];
                float e2 = nsel ? ((const float*)&g4[2])[i ^ 1] : ((const float*)&g4[2])[i];
                float e3 = nsel ? ((const float*)&g4[3])[i ^ 1] : ((const float*)&g4[3])[i];
                uint32_t h0, q0, h1, q1;
                split2(e0, e1, h0, q0);
                split2(e2, e3, h1, q1);
                int bi = n * 16 + ((bb ^ swz(n)) * 4) + bp;
                *(uint2*)&Bh[bi] = make_uint2(h0, h1);
                *(uint2*)&Bl[bi] = make_uint2(q0, q1);
            }
        }
        __syncthreads();

        bf16x8 vbh[4], vbl[4];
        #pragma unroll
        for (int fn = 0; fn < 4; fn++) {
            int br = wn * 64 + fn * 16 + l15;
            int bi = br * 16 + ((quad ^ swz(br)) * 4);
            vbh[fn] = *(const bf16x8*)&Bh[bi];
            vbl[fn] = *(const bf16x8*)&Bl[bi];
        }
        #pragma unroll
        for (int fm = 0; fm < 4; fm++) {
            int arow = wm * 64 + fm * 16 + l15;
            int ai = arow * 16 + ((quad ^ swz(arow)) * 4);
            bf16x8 vah = *(const bf16x8*)&Ah[ai];
            bf16x8 val = *(const bf16x8*)&Al[ai];
            #pragma unroll
            for (int fn = 0; fn < 4; fn++) {
                acc[fm][fn] = __builtin_amdgcn_mfma_f32_16x16x32_bf16(vbh[fn], vah, acc[fm][fn], 0, 0, 0);
                acc[fm][fn] = __builtin_amdgcn_mfma_f32_16x16x32_bf16(vbl[fn], vah, acc[fm][fn], 0, 0, 0);
                acc[fm][fn] = __builtin_amdgcn_mfma_f32_16x16x32_bf16(vbh[fn], val, acc[fm][fn], 0, 0, 0);
            }
        }
    }

    #pragma unroll
    for (int fm = 0; fm < 4; fm++) {
        int row = m0 + wm * 64 + fm * 16 + l15;
        #pragma unroll
        for (int fn = 0; fn < 4; fn++) {
            int colb = n0 + wn * 64 + fn * 16 + quad * 4;
            floatx4 a = acc[fm][fn];
            float4 v;
            if (kz == 0) {
                float4 bb4 = *(const float4*)&bias[colb];
                v.x = a[0] + bb4.x; v.y = a[1] + bb4.y;
                v.z = a[2] + bb4.z; v.w = a[3] + bb4.w;
                *(float4*)&Cf[(size_t)row * N + colb] = v;
            } else {
                v.x = a[0]; v.y = a[1]; v.z = a[2]; v.w = a[3];
                *(float4*)&P1[(size_t)row * N + colb] = v;
            }
        }
    }
}

// ---------------- combine: out += partial1 (L2/L3-resident, ~8us) -----------
__global__ __launch_bounds__(256)
void add_partial(const float4* __restrict__ p1, float4* __restrict__ out, int n4)
{
    int i = blockIdx.x * 256 + threadIdx.x;
    int stride = gridDim.x * 256;
    for (; i < n4; i += stride) {
        float4 a = out[i];
        float4 b = p1[i];
        a.x += b.x; a.y += b.y; a.z += b.z; a.w += b.w;
        out[i] = a;
    }
}

// ---------------- MFMA flash attention: QBLK=64, 4 blocks/CU ----------------
// R4 was latency-bound: nothing saturated (Mfma 28 / VALU 37 / LDS ~30%),
// occupancy grid-capped at 2 blocks/CU. Halving the Q-tile doubles the
// independent blocks per CU (1024 blocks, 34.8KB LDS each) so one block's
// softmax/barrier drains overlap another's MFMA.
#define FST 34
__global__ __launch_bounds__(256, 4)
void flash_attn(const uint32_t* __restrict__ qhg, const uint32_t* __restrict__ qlg,
                const uint32_t* __restrict__ khg, const uint32_t* __restrict__ klg,
                const uint32_t* __restrict__ vtg,
                uint32_t* __restrict__ xhg, uint32_t* __restrict__ xlg)
{
    __shared__ uint32_t Kh[64 * FST],  Kl[64 * FST];
    __shared__ uint32_t Vt[64 * FST];
    __shared__ uint32_t Pt[64 * FST];

    const int t    = threadIdx.x;
    const int lane = t & 63;
    const int w    = t >> 6;
    const int quad = lane >> 4, l15 = lane & 15;
    const int qb = blockIdx.x;          // 64-row Q tile
    const int h  = blockIdx.y;
    const int b  = blockIdx.z;

    const size_t rowbase = (size_t)b * SEQ;

    // ---- Q fragments: load once from global, keep in registers ----
    // wave w owns q-rows qb*64 + w*16 + l15 (16 rows)
    bf16x8 vqh[2], vql[2];     // [s]
    {
        size_t row = rowbase + qb * 64 + w * 16 + l15;
        size_t gw = row * 512 + h * 32 + quad * 4;
        #pragma unroll
        for (int s = 0; s < 2; s++) {
            vqh[s] = *(const bf16x8*)&qhg[gw + s * 16];
            vql[s] = *(const bf16x8*)&qlg[gw + s * 16];
        }
    }

    // ---- prefetch coords + tile kt=0 ----
    const int krow = t >> 2, kc0 = (t & 3) * 8;
    const int vd = t >> 2, vc = t & 3;
    const size_t vrow = (size_t)(h * 64 + vd) * 2048 + (rowbase >> 1);
    uint4 pkh0, pkh1, pkl0, pkl1;
    uint4 pv0, pv1;
    {
        size_t gw = (rowbase + krow) * 512 + h * 32 + kc0;
        pkh0 = *(const uint4*)&khg[gw];
        pkh1 = *(const uint4*)&khg[gw + 4];
        pkl0 = *(const uint4*)&klg[gw];
        pkl1 = *(const uint4*)&klg[gw + 4];
        size_t vw = vrow + vc * 8;
        pv0 = *(const uint4*)&vtg[vw];
        pv1 = *(const uint4*)&vtg[vw + 4];
    }

    float m_i = -INFINITY;
    float l_i = 0.0f;
    floatx4 acc_o[4];
    #pragma unroll
    for (int fm = 0; fm < 4; fm++)
        #pragma unroll
        for (int e = 0; e < 4; e++) acc_o[fm][e] = 0.0f;

    for (int kt = 0; kt < SEQ / 64; kt++) {
        __syncthreads();
        // ---- stage K from registers ----
        *(uint4*)&Kh[krow * FST + kc0]     = pkh0;
        *(uint4*)&Kh[krow * FST + kc0 + 4] = pkh1;
        *(uint4*)&Kl[krow * FST + kc0]     = pkl0;
        *(uint4*)&Kl[krow * FST + kc0 + 4] = pkl1;
        // ---- stage V^T from registers (pure copy) ----
        {
            int vb0 = vd * FST + vc * 8;
            *(uint2*)&Vt[vb0]     = make_uint2(pv0.x, pv0.y);
            *(uint2*)&Vt[vb0 + 2] = make_uint2(pv0.z, pv0.w);
            *(uint2*)&Vt[vb0 + 4] = make_uint2(pv1.x, pv1.y);
            *(uint2*)&Vt[vb0 + 6] = make_uint2(pv1.z, pv1.w);
        }
        __syncthreads();

        // ---- prefetch tile kt+1 (completes during compute) ----
        if (kt + 1 < SEQ / 64) {
            size_t gw = (rowbase + (kt + 1) * 64 + krow) * 512 + h * 32 + kc0;
            pkh0 = *(const uint4*)&khg[gw];
            pkh1 = *(const uint4*)&khg[gw + 4];
            pkl0 = *(const uint4*)&klg[gw];
            pkl1 = *(const uint4*)&klg[gw + 4];
            size_t vw = vrow + (kt + 1) * 32 + vc * 8;
            pv0 = *(const uint4*)&vtg[vw];
            pv1 = *(const uint4*)&vtg[vw + 4];
        }

        // ---- S^T = K·Q^T (bf16x3); K carries scale*log2e already ----
        floatx4 sacc[4];
        #pragma unroll
        for (int fm = 0; fm < 4; fm++)
            #pragma unroll
            for (int e = 0; e < 4; e++) sacc[fm][e] = 0.0f;

        __builtin_amdgcn_s_setprio(1);
        #pragma unroll
        for (int s = 0; s < 2; s++) {
            #pragma unroll
            for (int fm = 0; fm < 4; fm++) {
                int ki = (fm * 16 + l15) * FST + s * 16 + quad * 4;
                bf16x8 vkh = *(const bf16x8*)&Kh[ki];
                bf16x8 vkl = *(const bf16x8*)&Kl[ki];
                sacc[fm] = __builtin_amdgcn_mfma_f32_16x16x32_bf16(vkh, vqh[s], sacc[fm], 0, 0, 0);
                sacc[fm] = __builtin_amdgcn_mfma_f32_16x16x32_bf16(vkh, vql[s], sacc[fm], 0, 0, 0);
                sacc[fm] = __builtin_amdgcn_mfma_f32_16x16x32_bf16(vkl, vqh[s], sacc[fm], 0, 0, 0);
            }
        }
        __builtin_amdgcn_s_setprio(0);

        // ---- online softmax (base-2 domain, raw v_exp_f32) ----
        {
            float p[4][4];
            float mt = -INFINITY;
            #pragma unroll
            for (int fm = 0; fm < 4; fm++)
                #pragma unroll
                for (int r = 0; r < 4; r++) {
                    p[fm][r] = sacc[fm][r];
                    mt = fmaxf(mt, p[fm][r]);
                }
            mt = fmaxf(mt, __shfl_xor(mt, 16));
            mt = fmaxf(mt, __shfl_xor(mt, 32));
            float m_new = fmaxf(m_i, mt);
            float alpha = EXP2(m_i - m_new);
            float rs = 0.0f;
            #pragma unroll
            for (int fm = 0; fm < 4; fm++)
                #pragma unroll
                for (int r = 0; r < 4; r++) {
                    p[fm][r] = EXP2(p[fm][r] - m_new);
                    rs += p[fm][r];
                }
            rs += __shfl_xor(rs, 16);
            rs += __shfl_xor(rs, 32);
            l_i = l_i * alpha + rs;
            m_i = m_new;
            #pragma unroll
            for (int fm = 0; fm < 4; fm++)
                #pragma unroll
                for (int e = 0; e < 4; e++) acc_o[fm][e] *= alpha;

            int qrow = w * 16 + l15;
            #pragma unroll
            for (int fm = 0; fm < 4; fm++) {
                uint32_t u0 = pack_bf16_rne(p[fm][0], p[fm][1]);
                uint32_t u1 = pack_bf16_rne(p[fm][2], p[fm][3]);
                *(uint2*)&Pt[qrow * FST + fm * 8 + quad * 2] = make_uint2(u0, u1);
            }
        }

        // ---- O^T += Vt · P^T ----
        __builtin_amdgcn_s_setprio(1);
        #pragma unroll
        for (int s = 0; s < 2; s++) {
            bf16x8 pb = *(const bf16x8*)&Pt[(w * 16 + l15) * FST + s * 16 + quad * 4];
            #pragma unroll
            for (int fm = 0; fm < 4; fm++) {
                bf16x8 va = *(const bf16x8*)&Vt[(fm * 16 + l15) * FST + s * 16 + quad * 4];
                acc_o[fm] = __builtin_amdgcn_mfma_f32_16x16x32_bf16(va, pb, acc_o[fm], 0, 0, 0);
            }
        }
        __builtin_amdgcn_s_setprio(0);
    }

    // ---- epilogue: write x pre-split bf16 ----
    {
        float rl = 1.0f / l_i;
        size_t row = rowbase + qb * 64 + w * 16 + l15;
        #pragma unroll
        for (int fm = 0; fm < 4; fm++) {
            int d0 = fm * 16 + quad * 4;
            uint32_t h0, l0, h1, l1;
            split2(acc_o[fm][0] * rl, acc_o[fm][1] * rl, h0, l0);
            split2(acc_o[fm][2] * rl, acc_o[fm][3] * rl, h1, l1);
            size_t wi = row * 512 + ((h * 64 + d0) >> 1);
            *(uint2*)&xhg[wi] = make_uint2(h0, h1);
            *(uint2*)&xlg[wi] = make_uint2(l0, l1);
        }
    }
}

extern "C" void kernel_launch(void* const* d_in, const int* in_sizes, int n_in,
                              void* d_out, int out_size, void* d_ws, size_t ws_size,
                              hipStream_t stream)
{
    const float* input_qv = (const float*)d_in[0];
    const float* input_k  = (const float*)d_in[1];
    const float* W_qv     = (const float*)d_in[2];
    const float* W_k      = (const float*)d_in[3];
    const float* W_proj   = (const float*)d_in[4];
    const float* b_proj   = (const float*)d_in[5];
    float* out = (float*)d_out;

    const size_t RW = 4096 * 512;            // words per [4096][1024-bf16] buffer
    uint32_t* qh = (uint32_t*)d_ws;          // 5 RW = 41.9 MB total
    uint32_t* ql = qh + RW;
    uint32_t* vt = ql + RW;                  // V^T [16 h][64 d][4096 tok] bf16 = 1 RW
    uint32_t* xh = vt + RW;
    uint32_t* xl = xh + RW;
    uint32_t* kh = (uint32_t*)d_out;         // split K parked in d_out (16.8 MB);
    uint32_t* kl = kh + RW;                  // proj GEMM rewrites out afterwards
    float* p1 = (float*)d_ws;                // split-K partial: aliases qh/ql
                                             // (dead after flash_attn), 16.8 MB

    dim3 blk(256);
    // fused qv+k projections: 768 blocks = exactly 3/CU
    gemm_qvk<<<dim3(24, 32), blk, 0, stream>>>(
        input_qv, input_k, W_qv, W_k, qh, ql, (ushort*)vt, kh, kl);
    // flash attention: QBLK=64, 1024 blocks = 4/CU
    flash_attn<<<dim3(SEQ / 64, NH, BATCH), blk, 0, stream>>>(
        qh, ql, kh, kl, vt, xh, xl);
    // output projection + bias: split-K=2 at 128x128, 512 blocks
    gemm_projA<<<dim3(8, 32, 2), blk, 0, stream>>>(
        xh, xl, W_proj, b_proj, out, p1);
    // out += partial1
    add_partial<<<dim3(2048), blk, 0, stream>>>(
        (const float4*)p1, (float4*)out, 4096 * 1024 / 4);
}

// Round 6
// 309.842 us; speedup vs baseline: 1.2799x; 1.0081x over previous
//
#include <hip/hip_runtime.h>
#include <stdint.h>

#define BATCH 2
#define SEQ   2048
#define DIM   1024
#define NH    16
#define DH    64

typedef short bf16x8 __attribute__((ext_vector_type(8)));
typedef float floatx4 __attribute__((ext_vector_type(4)));

__device__ __forceinline__ int swz(int r) { return (r ^ (r >> 2)) & 3; }

// fast 2^x: raw v_exp_f32
#if __has_builtin(__builtin_amdgcn_exp2f)
#define EXP2(x) __builtin_amdgcn_exp2f(x)
#else
#define EXP2(x) __expf((x) * 0.6931471805599453f)
#endif

// Split two fp32 into packed bf16 hi-pair and lo-pair (truncation split)
__device__ __forceinline__ void split2(float x0, float x1, uint32_t& hi, uint32_t& lo) {
    uint32_t u0 = __float_as_uint(x0), u1 = __float_as_uint(x1);
    uint32_t m0 = u0 & 0xFFFF0000u;
    uint32_t m1 = u1 & 0xFFFF0000u;
    hi = (u0 >> 16) | m1;
    float l0 = x0 - __uint_as_float(m0);
    float l1 = x1 - __uint_as_float(m1);
    lo = (__float_as_uint(l0) >> 16) | (__float_as_uint(l1) & 0xFFFF0000u);
}

__device__ __forceinline__ uint32_t pack_bf16_rne(float x0, float x1) {
    uint32_t u0 = __float_as_uint(x0), u1 = __float_as_uint(x1);
    u0 += 0x7FFFu + ((u0 >> 16) & 1);
    u1 += 0x7FFFu + ((u1 >> 16) & 1);
    return (u0 >> 16) | (u1 & 0xFFFF0000u);
}

__device__ __forceinline__ ushort bf16_rne1(float x) {
    uint32_t u = __float_as_uint(x);
    u += 0x7FFFu + ((u >> 16) & 1);
    return (ushort)(u >> 16);
}

// softmax scale folded into K: 0.125 * log2(e) -> flash uses exp2
#define KSCALE 0.18033688011112042f

// ---------------- fused qv+k projection GEMM + register prefetch ------------
// T14: next k-step's A/B global loads issue right after the compute barrier,
// so HBM/L2 latency hides under the 48-MFMA compute phase instead of
// serializing each step (flash_attn's proven staging pattern).
__global__ __launch_bounds__(256, 3)
void gemm_qvk(const float* __restrict__ Aqv, const float* __restrict__ Akp,
              const float* __restrict__ Wqv, const float* __restrict__ Wkp,
              uint32_t* __restrict__ qh, uint32_t* __restrict__ ql,
              ushort* __restrict__ vt,
              uint32_t* __restrict__ kh, uint32_t* __restrict__ kl)
{
    __shared__ uint32_t Ah[128 * 16], Al[128 * 16], Bh[128 * 16], Bl[128 * 16];

    const int t    = threadIdx.x;
    const int lane = t & 63;
    const int w    = t >> 6;
    const int wm   = w & 1, wn = w >> 1;
    const int quad = lane >> 4, l15 = lane & 15;
    const int bx   = blockIdx.x;
    const bool is_qv = (bx < 16);
    const float* Af = is_qv ? Aqv : Akp;
    const float* Bf = is_qv ? Wqv : Wkp;
    const int N    = is_qv ? 2048 : 1024;
    const int n0   = (is_qv ? bx : bx - 16) * 128;
    const int m0   = blockIdx.y * 128;

    const int ar  = t >> 1;
    const int ab0 = (t & 1) * 2;
    const int as  = swz(ar);
    const int bc  = (t & 31) * 4;
    const int bk  = (t >> 5) * 4;
    const int bb  = bk >> 3;
    const int bp  = (bk & 7) >> 1;
    const bool nsel = ((bc >> 4) & 1) != 0;

    floatx4 acc[4][4];
    #pragma unroll
    for (int i = 0; i < 4; i++)
        #pragma unroll
        for (int j = 0; j < 4; j++)
            #pragma unroll
            for (int e = 0; e < 4; e++) acc[i][j][e] = 0.0f;

    // prefetch registers (static indexing only — scratch hazard otherwise)
    float f[16];
    float4 g4[4];
    {
        #pragma unroll
        for (int i = 0; i < 4; i++)
            *(float4*)&f[i * 4] =
                *(const float4*)&Af[(size_t)(m0 + ar) * 1024 + ab0 * 8 + i * 4];
        #pragma unroll
        for (int j = 0; j < 4; j++)
            g4[j] = *(const float4*)&Bf[(size_t)(bk + j) * N + n0 + bc];
    }

    for (int k0 = 0; k0 < 1024; k0 += 32) {
        if (k0) __syncthreads();
        // ---- stage A from registers ----
        {
            uint32_t hi[8], lo[8];
            #pragma unroll
            for (int j = 0; j < 8; j++) split2(f[2 * j], f[2 * j + 1], hi[j], lo[j]);
            int i0 = ar * 16 + ((ab0 ^ as) * 4);
            int i1 = ar * 16 + (((ab0 + 1) ^ as) * 4);
            *(uint4*)&Ah[i0] = make_uint4(hi[0], hi[1], hi[2], hi[3]);
            *(uint4*)&Ah[i1] = make_uint4(hi[4], hi[5], hi[6], hi[7]);
            *(uint4*)&Al[i0] = make_uint4(lo[0], lo[1], lo[2], lo[3]);
            *(uint4*)&Al[i1] = make_uint4(lo[4], lo[5], lo[6], lo[7]);
        }
        // ---- stage B from registers (conflict-min order, static extracts) --
        {
            #pragma unroll
            for (int i = 0; i < 4; i++) {
                int n = bc + (i ^ (nsel ? 1 : 0));
                float e0 = nsel ? ((const float*)&g4[0])[i ^ 1] : ((const float*)&g4[0])[i];
                float e1 = nsel ? ((const float*)&g4[1])[i ^ 1] : ((const float*)&g4[1])[i];
                float e2 = nsel ? ((const float*)&g4[2])[i ^ 1] : ((const float*)&g4[2])[i];
                float e3 = nsel ? ((const float*)&g4[3])[i ^ 1] : ((const float*)&g4[3])[i];
                uint32_t h0, q0, h1, q1;
                split2(e0, e1, h0, q0);
                split2(e2, e3, h1, q1);
                int bi = n * 16 + ((bb ^ swz(n)) * 4) + bp;
                *(uint2*)&Bh[bi] = make_uint2(h0, h1);
                *(uint2*)&Bl[bi] = make_uint2(q0, q1);
            }
        }
        __syncthreads();

        // ---- prefetch next k-step (completes during MFMA below) ----
        if (k0 + 32 < 1024) {
            #pragma unroll
            for (int i = 0; i < 4; i++)
                *(float4*)&f[i * 4] =
                    *(const float4*)&Af[(size_t)(m0 + ar) * 1024 + (k0 + 32) + ab0 * 8 + i * 4];
            #pragma unroll
            for (int j = 0; j < 4; j++)
                g4[j] = *(const float4*)&Bf[(size_t)(k0 + 32 + bk + j) * N + n0 + bc];
        }

        bf16x8 vbh[4], vbl[4];
        #pragma unroll
        for (int fn = 0; fn < 4; fn++) {
            int br = wn * 64 + fn * 16 + l15;
            int bi = br * 16 + ((quad ^ swz(br)) * 4);
            vbh[fn] = *(const bf16x8*)&Bh[bi];
            vbl[fn] = *(const bf16x8*)&Bl[bi];
        }
        #pragma unroll
        for (int fm = 0; fm < 4; fm++) {
            int arow = wm * 64 + fm * 16 + l15;
            int ai = arow * 16 + ((quad ^ swz(arow)) * 4);
            bf16x8 vah = *(const bf16x8*)&Ah[ai];
            bf16x8 val = *(const bf16x8*)&Al[ai];
            #pragma unroll
            for (int fn = 0; fn < 4; fn++) {
                acc[fm][fn] = __builtin_amdgcn_mfma_f32_16x16x32_bf16(vbh[fn], vah, acc[fm][fn], 0, 0, 0);
                acc[fm][fn] = __builtin_amdgcn_mfma_f32_16x16x32_bf16(vbl[fn], vah, acc[fm][fn], 0, 0, 0);
                acc[fm][fn] = __builtin_amdgcn_mfma_f32_16x16x32_bf16(vbh[fn], val, acc[fm][fn], 0, 0, 0);
            }
        }
    }

    #pragma unroll
    for (int fm = 0; fm < 4; fm++) {
        int row = m0 + wm * 64 + fm * 16 + l15;
        #pragma unroll
        for (int fn = 0; fn < 4; fn++) {
            int colb = n0 + wn * 64 + fn * 16 + quad * 4;
            floatx4 a = acc[fm][fn];
            if (is_qv) {
                if (colb < 1024) {
                    uint32_t h0, l0, h1, l1;
                    split2(a[0], a[1], h0, l0);
                    split2(a[2], a[3], h1, l1);
                    size_t wi = (size_t)row * 512 + (colb >> 1);
                    *(uint2*)&qh[wi] = make_uint2(h0, h1);
                    *(uint2*)&ql[wi] = make_uint2(l0, l1);
                } else {
                    // V transposed: vt[h][d][token] bf16
                    int hh = (colb - 1024) >> 6;
                    int d0 = (colb - 1024) & 63;
                    #pragma unroll
                    for (int j = 0; j < 4; j++)
                        vt[(size_t)(hh * 64 + d0 + j) * 4096 + row] = bf16_rne1(a[j]);
                }
            } else {
                // K pre-scaled by KSCALE (softmax scale * log2e folded in)
                uint32_t h0, l0, h1, l1;
                split2(a[0] * KSCALE, a[1] * KSCALE, h0, l0);
                split2(a[2] * KSCALE, a[3] * KSCALE, h1, l1);
                size_t wi = (size_t)row * 512 + (colb >> 1);
                *(uint2*)&kh[wi] = make_uint2(h0, h1);
                *(uint2*)&kl[wi] = make_uint2(l0, l1);
            }
        }
    }
}

// ---------------- proj GEMM: split-K=2 at 128x128 + register prefetch -------
__global__ __launch_bounds__(256, 3)
void gemm_projA(const uint32_t* __restrict__ Ahg, const uint32_t* __restrict__ Alg,
                const float* __restrict__ Bf, const float* __restrict__ bias,
                float* __restrict__ Cf, float* __restrict__ P1)
{
    __shared__ uint32_t Ah[128 * 16], Al[128 * 16], Bh[128 * 16], Bl[128 * 16];

    const int t    = threadIdx.x;
    const int lane = t & 63;
    const int w    = t >> 6;
    const int wm   = w & 1, wn = w >> 1;
    const int quad = lane >> 4, l15 = lane & 15;
    const int m0 = blockIdx.y * 128, n0 = blockIdx.x * 128;
    const int kz = blockIdx.z;
    const int k0 = kz * 512;
    const int N  = 1024;

    const int bc  = (t & 31) * 4;
    const int bk  = (t >> 5) * 4;
    const int bb  = bk >> 3;
    const int bp  = (bk & 7) >> 1;
    const bool nsel = ((bc >> 4) & 1) != 0;

    // A-staging coords
    const int arow0 = t >> 2, akbl = t & 3;
    const int arow1 = (t + 256) >> 2;

    floatx4 acc[4][4];
    #pragma unroll
    for (int i = 0; i < 4; i++)
        #pragma unroll
        for (int j = 0; j < 4; j++)
            #pragma unroll
            for (int e = 0; e < 4; e++) acc[i][j][e] = 0.0f;

    // prefetch registers
    uint4 gAh0, gAh1, gAl0, gAl1;
    float4 g4[4];
    {
        size_t s0 = (size_t)(m0 + arow0) * 512 + (k0 >> 1) + akbl * 4;
        size_t s1 = (size_t)(m0 + arow1) * 512 + (k0 >> 1) + akbl * 4;
        gAh0 = *(const uint4*)&Ahg[s0];
        gAl0 = *(const uint4*)&Alg[s0];
        gAh1 = *(const uint4*)&Ahg[s1];
        gAl1 = *(const uint4*)&Alg[s1];
        #pragma unroll
        for (int j = 0; j < 4; j++)
            g4[j] = *(const float4*)&Bf[(size_t)(k0 + bk + j) * N + n0 + bc];
    }

    for (int kk = 0; kk < 512; kk += 32) {
        if (kk) __syncthreads();
        // ---- stage A from registers ----
        {
            int dst0 = arow0 * 16 + ((akbl ^ swz(arow0)) * 4);
            int dst1 = arow1 * 16 + ((akbl ^ swz(arow1)) * 4);
            *(uint4*)&Ah[dst0] = gAh0;
            *(uint4*)&Al[dst0] = gAl0;
            *(uint4*)&Ah[dst1] = gAh1;
            *(uint4*)&Al[dst1] = gAl1;
        }
        // ---- stage B from registers ----
        {
            #pragma unroll
            for (int i = 0; i < 4; i++) {
                int n = bc + (i ^ (nsel ? 1 : 0));
                float e0 = nsel ? ((const float*)&g4[0])[i ^ 1] : ((const float*)&g4[0])[i];
                float e1 = nsel ? ((const float*)&g4[1])[i ^ 1] : ((const float*)&g4[1])[i];
                float e2 = nsel ? ((const float*)&g4[2])[i ^ 1] : ((const float*)&g4[2])[i];
                float e3 = nsel ? ((const float*)&g4[3])[i ^ 1] : ((const float*)&g4[3])[i];
                uint32_t h0, q0, h1, q1;
                split2(e0, e1, h0, q0);
                split2(e2, e3, h1, q1);
                int bi = n * 16 + ((bb ^ swz(n)) * 4) + bp;
                *(uint2*)&Bh[bi] = make_uint2(h0, h1);
                *(uint2*)&Bl[bi] = make_uint2(q0, q1);
            }
        }
        __syncthreads();

        // ---- prefetch next k-step ----
        if (kk + 32 < 512) {
            const int kg = k0 + kk + 32;
            size_t s0 = (size_t)(m0 + arow0) * 512 + (kg >> 1) + akbl * 4;
            size_t s1 = (size_t)(m0 + arow1) * 512 + (kg >> 1) + akbl * 4;
            gAh0 = *(const uint4*)&Ahg[s0];
            gAl0 = *(const uint4*)&Alg[s0];
            gAh1 = *(const uint4*)&Ahg[s1];
            gAl1 = *(const uint4*)&Alg[s1];
            #pragma unroll
            for (int j = 0; j < 4; j++)
                g4[j] = *(const float4*)&Bf[(size_t)(kg + bk + j) * N + n0 + bc];
        }

        bf16x8 vbh[4], vbl[4];
        #pragma unroll
        for (int fn = 0; fn < 4; fn++) {
            int br = wn * 64 + fn * 16 + l15;
            int bi = br * 16 + ((quad ^ swz(br)) * 4);
            vbh[fn] = *(const bf16x8*)&Bh[bi];
            vbl[fn] = *(const bf16x8*)&Bl[bi];
        }
        #pragma unroll
        for (int fm = 0; fm < 4; fm++) {
            int arow = wm * 64 + fm * 16 + l15;
            int ai = arow * 16 + ((quad ^ swz(arow)) * 4);
            bf16x8 vah = *(const bf16x8*)&Ah[ai];
            bf16x8 val = *(const bf16x8*)&Al[ai];
            #pragma unroll
            for (int fn = 0; fn < 4; fn++) {
                acc[fm][fn] = __builtin_amdgcn_mfma_f32_16x16x32_bf16(vbh[fn], vah, acc[fm][fn], 0, 0, 0);
                acc[fm][fn] = __builtin_amdgcn_mfma_f32_16x16x32_bf16(vbl[fn], vah, acc[fm][fn], 0, 0, 0);
                acc[fm][fn] = __builtin_amdgcn_mfma_f32_16x16x32_bf16(vbh[fn], val, acc[fm][fn], 0, 0, 0);
            }
        }
    }

    #pragma unroll
    for (int fm = 0; fm < 4; fm++) {
        int row = m0 + wm * 64 + fm * 16 + l15;
        #pragma unroll
        for (int fn = 0; fn < 4; fn++) {
            int colb = n0 + wn * 64 + fn * 16 + quad * 4;
            floatx4 a = acc[fm][fn];
            float4 v;
            if (kz == 0) {
                float4 bb4 = *(const float4*)&bias[colb];
                v.x = a[0] + bb4.x; v.y = a[1] + bb4.y;
                v.z = a[2] + bb4.z; v.w = a[3] + bb4.w;
                *(float4*)&Cf[(size_t)row * N + colb] = v;
            } else {
                v.x = a[0]; v.y = a[1]; v.z = a[2]; v.w = a[3];
                *(float4*)&P1[(size_t)row * N + colb] = v;
            }
        }
    }
}

// ---------------- combine: out += partial1 (L2/L3-resident) -----------------
__global__ __launch_bounds__(256)
void add_partial(const float4* __restrict__ p1, float4* __restrict__ out, int n4)
{
    int i = blockIdx.x * 256 + threadIdx.x;
    int stride = gridDim.x * 256;
    for (; i < n4; i += stride) {
        float4 a = out[i];
        float4 b = p1[i];
        a.x += b.x; a.y += b.y; a.z += b.z; a.w += b.w;
        out[i] = a;
    }
}

// ---------------- MFMA flash attention (R4-proven: QBLK=128, Q in regs) -----
#define FST 34
__global__ __launch_bounds__(256, 2)
void flash_attn(const uint32_t* __restrict__ qhg, const uint32_t* __restrict__ qlg,
                const uint32_t* __restrict__ khg, const uint32_t* __restrict__ klg,
                const uint32_t* __restrict__ vtg,
                uint32_t* __restrict__ xhg, uint32_t* __restrict__ xlg)
{
    __shared__ uint32_t Kh[64 * FST],  Kl[64 * FST];
    __shared__ uint32_t Vt[64 * FST];
    __shared__ uint32_t Pt[128 * FST];

    const int t    = threadIdx.x;
    const int lane = t & 63;
    const int w    = t >> 6;
    const int quad = lane >> 4, l15 = lane & 15;
    const int qb = blockIdx.x;
    const int h  = blockIdx.y;
    const int b  = blockIdx.z;

    const size_t rowbase = (size_t)b * SEQ;

    // ---- Q fragments: load once from global, keep in registers ----
    bf16x8 vqh[2][2], vql[2][2];     // [s][nf]
    {
        #pragma unroll
        for (int nf = 0; nf < 2; nf++) {
            size_t row = rowbase + qb * 128 + w * 32 + nf * 16 + l15;
            size_t gw = row * 512 + h * 32 + quad * 4;
            #pragma unroll
            for (int s = 0; s < 2; s++) {
                vqh[s][nf] = *(const bf16x8*)&qhg[gw + s * 16];
                vql[s][nf] = *(const bf16x8*)&qlg[gw + s * 16];
            }
        }
    }

    // ---- prefetch coords + tile kt=0 ----
    const int krow = t >> 2, kc0 = (t & 3) * 8;
    const int vd = t >> 2, vc = t & 3;
    const size_t vrow = (size_t)(h * 64 + vd) * 2048 + (rowbase >> 1);
    uint4 pkh0, pkh1, pkl0, pkl1;
    uint4 pv0, pv1;
    {
        size_t gw = (rowbase + krow) * 512 + h * 32 + kc0;
        pkh0 = *(const uint4*)&khg[gw];
        pkh1 = *(const uint4*)&khg[gw + 4];
        pkl0 = *(const uint4*)&klg[gw];
        pkl1 = *(const uint4*)&klg[gw + 4];
        size_t vw = vrow + vc * 8;
        pv0 = *(const uint4*)&vtg[vw];
        pv1 = *(const uint4*)&vtg[vw + 4];
    }

    float m_i[2] = {-INFINITY, -INFINITY};
    float l_i[2] = {0.0f, 0.0f};
    floatx4 acc_o[2][4];
    #pragma unroll
    for (int nf = 0; nf < 2; nf++)
        #pragma unroll
        for (int fm = 0; fm < 4; fm++)
            #pragma unroll
            for (int e = 0; e < 4; e++) acc_o[nf][fm][e] = 0.0f;

    for (int kt = 0; kt < SEQ / 64; kt++) {
        __syncthreads();
        // ---- stage K from registers ----
        *(uint4*)&Kh[krow * FST + kc0]     = pkh0;
        *(uint4*)&Kh[krow * FST + kc0 + 4] = pkh1;
        *(uint4*)&Kl[krow * FST + kc0]     = pkl0;
        *(uint4*)&Kl[krow * FST + kc0 + 4] = pkl1;
        // ---- stage V^T from registers (pure copy) ----
        {
            int vb0 = vd * FST + vc * 8;
            *(uint2*)&Vt[vb0]     = make_uint2(pv0.x, pv0.y);
            *(uint2*)&Vt[vb0 + 2] = make_uint2(pv0.z, pv0.w);
            *(uint2*)&Vt[vb0 + 4] = make_uint2(pv1.x, pv1.y);
            *(uint2*)&Vt[vb0 + 6] = make_uint2(pv1.z, pv1.w);
        }
        __syncthreads();

        // ---- prefetch tile kt+1 (completes during compute) ----
        if (kt + 1 < SEQ / 64) {
            size_t gw = (rowbase + (kt + 1) * 64 + krow) * 512 + h * 32 + kc0;
            pkh0 = *(const uint4*)&khg[gw];
            pkh1 = *(const uint4*)&khg[gw + 4];
            pkl0 = *(const uint4*)&klg[gw];
            pkl1 = *(const uint4*)&klg[gw + 4];
            size_t vw = vrow + (kt + 1) * 32 + vc * 8;
            pv0 = *(const uint4*)&vtg[vw];
            pv1 = *(const uint4*)&vtg[vw + 4];
        }

        // ---- S^T = K·Q^T (bf16x3); K carries scale*log2e already ----
        floatx4 sacc[2][4];
        #pragma unroll
        for (int nf = 0; nf < 2; nf++)
            #pragma unroll
            for (int fm = 0; fm < 4; fm++)
                #pragma unroll
                for (int e = 0; e < 4; e++) sacc[nf][fm][e] = 0.0f;

        __builtin_amdgcn_s_setprio(1);
        #pragma unroll
        for (int s = 0; s < 2; s++) {
            #pragma unroll
            for (int fm = 0; fm < 4; fm++) {
                int ki = (fm * 16 + l15) * FST + s * 16 + quad * 4;
                bf16x8 vkh = *(const bf16x8*)&Kh[ki];
                bf16x8 vkl = *(const bf16x8*)&Kl[ki];
                #pragma unroll
                for (int nf = 0; nf < 2; nf++) {
                    sacc[nf][fm] = __builtin_amdgcn_mfma_f32_16x16x32_bf16(vkh, vqh[s][nf], sacc[nf][fm], 0, 0, 0);
                    sacc[nf][fm] = __builtin_amdgcn_mfma_f32_16x16x32_bf16(vkh, vql[s][nf], sacc[nf][fm], 0, 0, 0);
                    sacc[nf][fm] = __builtin_amdgcn_mfma_f32_16x16x32_bf16(vkl, vqh[s][nf], sacc[nf][fm], 0, 0, 0);
                }
            }
        }
        __builtin_amdgcn_s_setprio(0);

        // ---- online softmax (base-2 domain, raw v_exp_f32) ----
        #pragma unroll
        for (int nf = 0; nf < 2; nf++) {
            float p[4][4];
            float mt = -INFINITY;
            #pragma unroll
            for (int fm = 0; fm < 4; fm++)
                #pragma unroll
                for (int r = 0; r < 4; r++) {
                    p[fm][r] = sacc[nf][fm][r];
                    mt = fmaxf(mt, p[fm][r]);
                }
            mt = fmaxf(mt, __shfl_xor(mt, 16));
            mt = fmaxf(mt, __shfl_xor(mt, 32));
            float m_new = fmaxf(m_i[nf], mt);
            float alpha = EXP2(m_i[nf] - m_new);
            float rs = 0.0f;
            #pragma unroll
            for (int fm = 0; fm < 4; fm++)
                #pragma unroll
                for (int r = 0; r < 4; r++) {
                    p[fm][r] = EXP2(p[fm][r] - m_new);
                    rs += p[fm][r];
                }
            rs += __shfl_xor(rs, 16);
            rs += __shfl_xor(rs, 32);
            l_i[nf] = l_i[nf] * alpha + rs;
            m_i[nf] = m_new;
            #pragma unroll
            for (int fm = 0; fm < 4; fm++)
                #pragma unroll
                for (int e = 0; e < 4; e++) acc_o[nf][fm][e] *= alpha;

            int qrow = w * 32 + nf * 16 + l15;
            #pragma unroll
            for (int fm = 0; fm < 4; fm++) {
                uint32_t u0 = pack_bf16_rne(p[fm][0], p[fm][1]);
                uint32_t u1 = pack_bf16_rne(p[fm][2], p[fm][3]);
                *(uint2*)&Pt[qrow * FST + fm * 8 + quad * 2] = make_uint2(u0, u1);
            }
        }

        // ---- O^T += Vt · P^T ----
        __builtin_amdgcn_s_setprio(1);
        #pragma unroll
        for (int s = 0; s < 2; s++) {
            bf16x8 pb[2];
            #pragma unroll
            for (int nf = 0; nf < 2; nf++)
                pb[nf] = *(const bf16x8*)&Pt[(w * 32 + nf * 16 + l15) * FST + s * 16 + quad * 4];
            #pragma unroll
            for (int fm = 0; fm < 4; fm++) {
                bf16x8 va = *(const bf16x8*)&Vt[(fm * 16 + l15) * FST + s * 16 + quad * 4];
                #pragma unroll
                for (int nf = 0; nf < 2; nf++)
                    acc_o[nf][fm] = __builtin_amdgcn_mfma_f32_16x16x32_bf16(va, pb[nf], acc_o[nf][fm], 0, 0, 0);
            }
        }
        __builtin_amdgcn_s_setprio(0);
    }

    // ---- epilogue: write x pre-split bf16 ----
    #pragma unroll
    for (int nf = 0; nf < 2; nf++) {
        float rl = 1.0f / l_i[nf];
        size_t row = rowbase + qb * 128 + w * 32 + nf * 16 + l15;
        #pragma unroll
        for (int fm = 0; fm < 4; fm++) {
            int d0 = fm * 16 + quad * 4;
            uint32_t h0, l0, h1, l1;
            split2(acc_o[nf][fm][0] * rl, acc_o[nf][fm][1] * rl, h0, l0);
            split2(acc_o[nf][fm][2] * rl, acc_o[nf][fm][3] * rl, h1, l1);
            size_t wi = row * 512 + ((h * 64 + d0) >> 1);
            *(uint2*)&xhg[wi] = make_uint2(h0, h1);
            *(uint2*)&xlg[wi] = make_uint2(l0, l1);
        }
    }
}

extern "C" void kernel_launch(void* const* d_in, const int* in_sizes, int n_in,
                              void* d_out, int out_size, void* d_ws, size_t ws_size,
                              hipStream_t stream)
{
    const float* input_qv = (const float*)d_in[0];
    const float* input_k  = (const float*)d_in[1];
    const float* W_qv     = (const float*)d_in[2];
    const float* W_k      = (const float*)d_in[3];
    const float* W_proj   = (const float*)d_in[4];
    const float* b_proj   = (const float*)d_in[5];
    float* out = (float*)d_out;

    const size_t RW = 4096 * 512;            // words per [4096][1024-bf16] buffer
    uint32_t* qh = (uint32_t*)d_ws;          // 5 RW = 41.9 MB total
    uint32_t* ql = qh + RW;
    uint32_t* vt = ql + RW;                  // V^T [16 h][64 d][4096 tok] bf16 = 1 RW
    uint32_t* xh = vt + RW;
    uint32_t* xl = xh + RW;
    uint32_t* kh = (uint32_t*)d_out;         // split K parked in d_out (16.8 MB);
    uint32_t* kl = kh + RW;                  // proj GEMM rewrites out afterwards
    float* p1 = (float*)d_ws;                // split-K partial: aliases qh/ql
                                             // (dead after flash_attn), 16.8 MB

    dim3 blk(256);
    // fused qv+k projections: 768 blocks = exactly 3/CU
    gemm_qvk<<<dim3(24, 32), blk, 0, stream>>>(
        input_qv, input_k, W_qv, W_k, qh, ql, (ushort*)vt, kh, kl);
    // flash attention: QBLK=128 (R4-proven), 512 blocks
    flash_attn<<<dim3(SEQ / 128, NH, BATCH), blk, 0, stream>>>(
        qh, ql, kh, kl, vt, xh, xl);
    // output projection + bias: split-K=2 at 128x128, 512 blocks
    gemm_projA<<<dim3(8, 32, 2), blk, 0, stream>>>(
        xh, xl, W_proj, b_proj, out, p1);
    // out += partial1
    add_partial<<<dim3(2048), blk, 0, stream>>>(
        (const float4*)p1, (float4*)out, 4096 * 1024 / 4);
}